// Round 1
// baseline (2213.400 us; speedup 1.0000x reference)
//
#include <hip/hip_runtime.h>
#include <math.h>

// ---------------------------------------------------------------------------
// StatusGCN: 3-layer GCN-ish pipeline.
//   h0 = x @ W1                     [N,256]
//   h1 = relu(spmm(h0) + b1)        [N,256]
//   h2 = spmm(h1 @ W2) + b2         [N,64]
//   out = log_softmax(spmm(h2 @ W3) + r)   [N,64]
// spmm is pull-mode over a dst-sorted CSR built per launch (no fp atomics).
// ---------------------------------------------------------------------------

// ---------------- CSR construction ----------------

__global__ void count_edges(const int* __restrict__ dst, int* __restrict__ cnt, int E) {
    int e = blockIdx.x * 256 + threadIdx.x;
    if (e < E) atomicAdd(&cnt[dst[e]], 1);
}

__global__ __launch_bounds__(1024) void scan_counts(const int* __restrict__ cnt,
                                                    int* __restrict__ rp, int n) {
    __shared__ int sd[1024];
    __shared__ int carry;
    int tid = threadIdx.x;
    if (tid == 0) carry = 0;
    __syncthreads();
    for (int base = 0; base < n; base += 1024) {
        int i = base + tid;
        int v = (i < n) ? cnt[i] : 0;
        sd[tid] = v;
        __syncthreads();
        for (int off = 1; off < 1024; off <<= 1) {
            int t = (tid >= off) ? sd[tid - off] : 0;
            __syncthreads();
            sd[tid] += t;
            __syncthreads();
        }
        if (i < n) rp[i] = carry + sd[tid] - v;   // exclusive prefix
        __syncthreads();
        if (tid == 0) carry += sd[1023];
        __syncthreads();
    }
    if (tid == 0) rp[n] = carry;
}

__global__ void scatter_edges(const int* __restrict__ src, const int* __restrict__ dst,
                              const float* __restrict__ ew, const int* __restrict__ rp,
                              int* __restrict__ tmp, int* __restrict__ se,
                              float* __restrict__ we, int E) {
    int e = blockIdx.x * 256 + threadIdx.x;
    if (e < E) {
        int d = dst[e];
        int pos = rp[d] + atomicAdd(&tmp[d], 1);
        se[pos] = src[e];
        we[pos] = ew[e];
    }
}

// ---------------- dense GEMM (fp32, 64x64 tile) ----------------
// C[M,Nn] = A[M,K] @ B[K,Nn].  Nn % 64 == 0, K % 16 == 0, M guarded.

__global__ __launch_bounds__(256) void gemm64(const float* __restrict__ A,
                                              const float* __restrict__ B,
                                              float* __restrict__ C,
                                              int M, int Nn, int K) {
    __shared__ float As[16][68];   // [k][m], +4 pad keeps 16B alignment, breaks conflicts
    __shared__ float Bs[16][64];   // [k][n]
    const int tid = threadIdx.x;
    const int tx = tid & 15, ty = tid >> 4;
    const int bm = blockIdx.x * 64, bn = blockIdx.y * 64;
    float acc[4][4] = {};
    for (int k0 = 0; k0 < K; k0 += 16) {
#pragma unroll
        for (int i = 0; i < 4; ++i) {
            int idx = tid + i * 256;           // 0..1023
            int m = idx >> 4, kk = idx & 15;   // A tile 64x16
            int gm = bm + m;
            As[kk][m] = (gm < M) ? A[(size_t)gm * K + k0 + kk] : 0.f;
            int kb = idx >> 6, n = idx & 63;   // B tile 16x64
            Bs[kb][n] = B[(size_t)(k0 + kb) * Nn + bn + n];
        }
        __syncthreads();
#pragma unroll
        for (int kk = 0; kk < 16; ++kk) {
            float a[4], b[4];
#pragma unroll
            for (int i = 0; i < 4; ++i) a[i] = As[kk][ty * 4 + i];
#pragma unroll
            for (int j = 0; j < 4; ++j) b[j] = Bs[kk][tx * 4 + j];
#pragma unroll
            for (int i = 0; i < 4; ++i)
#pragma unroll
                for (int j = 0; j < 4; ++j) acc[i][j] = fmaf(a[i], b[j], acc[i][j]);
        }
        __syncthreads();
    }
#pragma unroll
    for (int i = 0; i < 4; ++i) {
        int row = bm + ty * 4 + i;
        if (row < M) {
            float4 v = make_float4(acc[i][0], acc[i][1], acc[i][2], acc[i][3]);
            *(float4*)(C + (size_t)row * Nn + bn + tx * 4) = v;
        }
    }
}

// ---------------- pull-mode SpMM ----------------
// one wave per dst node; 256-feature variant: lane handles 4 floats.

__global__ __launch_bounds__(256) void spmm256(const float* __restrict__ h,
                                               const int* __restrict__ rp,
                                               const int* __restrict__ se,
                                               const float* __restrict__ we,
                                               const float* __restrict__ bias,
                                               float* __restrict__ out, int n, int do_relu) {
    int node = blockIdx.x * 4 + (threadIdx.x >> 6);
    if (node >= n) return;
    int lane = threadIdx.x & 63;
    int e0 = rp[node], e1 = rp[node + 1];
    float4 acc = make_float4(0.f, 0.f, 0.f, 0.f);
    for (int e = e0; e < e1; ++e) {
        int s = se[e];
        float w = we[e];
        const float4 v = *(const float4*)(h + (size_t)s * 256 + lane * 4);
        acc.x = fmaf(w, v.x, acc.x);
        acc.y = fmaf(w, v.y, acc.y);
        acc.z = fmaf(w, v.z, acc.z);
        acc.w = fmaf(w, v.w, acc.w);
    }
    const float4 b = *(const float4*)(bias + lane * 4);
    acc.x += b.x; acc.y += b.y; acc.z += b.z; acc.w += b.w;
    if (do_relu) {
        acc.x = fmaxf(acc.x, 0.f); acc.y = fmaxf(acc.y, 0.f);
        acc.z = fmaxf(acc.z, 0.f); acc.w = fmaxf(acc.w, 0.f);
    }
    *(float4*)(out + (size_t)node * 256 + lane * 4) = acc;
}

// 64-feature variant: lane == feature; optional fused log_softmax (wave owns row).
__global__ __launch_bounds__(256) void spmm64(const float* __restrict__ h,
                                              const int* __restrict__ rp,
                                              const int* __restrict__ se,
                                              const float* __restrict__ we,
                                              const float* __restrict__ bias,
                                              float* __restrict__ out, int n, int do_lse) {
    int node = blockIdx.x * 4 + (threadIdx.x >> 6);
    if (node >= n) return;
    int lane = threadIdx.x & 63;
    int e0 = rp[node], e1 = rp[node + 1];
    float acc = 0.f;
    for (int e = e0; e < e1; ++e) {
        acc = fmaf(we[e], h[(size_t)se[e] * 64 + lane], acc);
    }
    acc += bias[lane];
    if (do_lse) {
        float m = acc;
#pragma unroll
        for (int off = 32; off > 0; off >>= 1) m = fmaxf(m, __shfl_xor(m, off));
        float ex = __expf(acc - m);
        float s = ex;
#pragma unroll
        for (int off = 32; off > 0; off >>= 1) s += __shfl_xor(s, off);
        acc = acc - m - __logf(s);
    }
    out[(size_t)node * 64 + lane] = acc;
}

// ---------------------------------------------------------------------------

extern "C" void kernel_launch(void* const* d_in, const int* in_sizes, int n_in,
                              void* d_out, int out_size, void* d_ws, size_t ws_size,
                              hipStream_t stream) {
    const float* x  = (const float*)d_in[0];
    const int*   src = (const int*)d_in[1];
    const int*   dst = (const int*)d_in[2];
    const float* ew = (const float*)d_in[3];
    const float* W1 = (const float*)d_in[4];
    const float* b1 = (const float*)d_in[5];
    const float* W2 = (const float*)d_in[6];
    const float* b2 = (const float*)d_in[7];
    const float* W3 = (const float*)d_in[8];
    const float* r  = (const float*)d_in[9];

    const int N = in_sizes[0] / 512;   // 100000
    const int E = in_sizes[1];         // 3200000

    // workspace layout (fp32 elements unless noted):
    //   h0   : N*256   (also reused as 4x N*64 scratch after spmm1)
    //   h1   : N*256
    //   rp   : N+1 int
    //   tmp  : N   int
    //   se   : E   int
    //   we   : E   f32
    float* h0   = (float*)d_ws;
    float* h1   = h0 + (size_t)N * 256;
    float* h2in = h0;                          // reuse h0 region after spmm1
    float* g2   = h0 + (size_t)N * 64;
    float* h3in = h0 + (size_t)2 * N * 64;
    int*   rp   = (int*)(h1 + (size_t)N * 256);
    int*   tmp  = rp + (N + 1);
    int*   se   = tmp + N;
    float* we   = (float*)(se + E);

    // ---- build dst-sorted CSR (structure identical for all 3 spmms) ----
    hipMemsetAsync(tmp, 0, (size_t)N * sizeof(int), stream);
    count_edges<<<(E + 255) / 256, 256, 0, stream>>>(dst, tmp, E);
    scan_counts<<<1, 1024, 0, stream>>>(tmp, rp, N);
    hipMemsetAsync(tmp, 0, (size_t)N * sizeof(int), stream);
    scatter_edges<<<(E + 255) / 256, 256, 0, stream>>>(src, dst, ew, rp, tmp, se, we, E);

    // ---- layer 1 ----
    dim3 grid1((N + 63) / 64, 256 / 64);
    gemm64<<<grid1, 256, 0, stream>>>(x, W1, h0, N, 256, 512);
    spmm256<<<(N + 3) / 4, 256, 0, stream>>>(h0, rp, se, we, b1, h1, N, 1);

    // ---- layer 2 ----
    dim3 grid2((N + 63) / 64, 1);
    gemm64<<<grid2, 256, 0, stream>>>(h1, W2, h2in, N, 64, 256);
    spmm64<<<(N + 3) / 4, 256, 0, stream>>>(h2in, rp, se, we, b2, g2, N, 0);

    // ---- layer 3 + fused log_softmax ----
    gemm64<<<grid2, 256, 0, stream>>>(g2, W3, h3in, N, 64, 64);
    spmm64<<<(N + 3) / 4, 256, 0, stream>>>(h3in, rp, se, we, r, (float*)d_out, N, 1);
}

// Round 2
// 1649.598 us; speedup vs baseline: 1.3418x; 1.3418x over previous
//
#include <hip/hip_runtime.h>
#include <math.h>

// ---------------------------------------------------------------------------
// StatusGCN pipeline:
//   h0 = bf16(x @ W1)  (MFMA bf16)        [N,256] bf16
//   h1 = relu(spmm(h0) + b1)              [N,256] fp32
//   h2 = spmm(h1 @ W2) + b2               [N,64]  fp32
//   out = log_softmax(spmm(h2 @ W3) + r)  [N,64]  fp32
// spmm: pull-mode over dst-sorted CSR rebuilt each launch (ws is re-poisoned).
// ---------------------------------------------------------------------------

typedef __bf16 bf16x8 __attribute__((ext_vector_type(8)));
typedef float f32x4 __attribute__((ext_vector_type(4)));

__device__ __forceinline__ float bf2f(unsigned short s) {
    return __uint_as_float(((unsigned)s) << 16);
}

// ---------------- CSR construction ----------------

__global__ void count_edges(const int* __restrict__ dst, int* __restrict__ cnt, int E) {
    int e = blockIdx.x * 256 + threadIdx.x;
    if (e < E) atomicAdd(&cnt[dst[e]], 1);
}

__global__ __launch_bounds__(1024) void scan_counts(const int* __restrict__ cnt,
                                                    int* __restrict__ rp, int n) {
    __shared__ int sd[1024];
    __shared__ int carry;
    int tid = threadIdx.x;
    if (tid == 0) carry = 0;
    __syncthreads();
    for (int base = 0; base < n; base += 4096) {
        int i0 = base + tid * 4;
        int c0 = (i0     < n) ? cnt[i0]     : 0;
        int c1 = (i0 + 1 < n) ? cnt[i0 + 1] : 0;
        int c2 = (i0 + 2 < n) ? cnt[i0 + 2] : 0;
        int c3 = (i0 + 3 < n) ? cnt[i0 + 3] : 0;
        int s = c0 + c1 + c2 + c3;
        sd[tid] = s;
        __syncthreads();
        for (int off = 1; off < 1024; off <<= 1) {
            int t = (tid >= off) ? sd[tid - off] : 0;
            __syncthreads();
            sd[tid] += t;
            __syncthreads();
        }
        int excl = carry + sd[tid] - s;   // exclusive prefix of this thread's group
        if (i0     < n) rp[i0]     = excl;
        if (i0 + 1 < n) rp[i0 + 1] = excl + c0;
        if (i0 + 2 < n) rp[i0 + 2] = excl + c0 + c1;
        if (i0 + 3 < n) rp[i0 + 3] = excl + c0 + c1 + c2;
        __syncthreads();
        if (tid == 0) carry += sd[1023];
        __syncthreads();
    }
    if (tid == 0) rp[n] = carry;
}

__global__ void scatter_edges(const int* __restrict__ src, const int* __restrict__ dst,
                              const float* __restrict__ ew, const int* __restrict__ rp,
                              int* __restrict__ tmp, int* __restrict__ se,
                              float* __restrict__ we, int E) {
    int e = blockIdx.x * 256 + threadIdx.x;
    if (e < E) {
        int d = dst[e];
        int pos = rp[d] + atomicAdd(&tmp[d], 1);
        se[pos] = src[e];
        we[pos] = ew[e];
    }
}

// ---------------- casts ----------------

__global__ __launch_bounds__(256) void cast_f32_bf16(const float* __restrict__ in,
                                                     __bf16* __restrict__ out, long n) {
    long i = ((long)blockIdx.x * 256 + threadIdx.x) * 4;
    if (i + 3 < n) {
        float4 v = *(const float4*)(in + i);
        out[i]     = (__bf16)v.x;
        out[i + 1] = (__bf16)v.y;
        out[i + 2] = (__bf16)v.z;
        out[i + 3] = (__bf16)v.w;
    } else {
        for (long j = i; j < n; ++j) out[j] = (__bf16)in[j];
    }
}

// W1 [K=512, Nn=256] fp32 -> W1T [Nn][K] bf16
__global__ __launch_bounds__(256) void cast_transpose(const float* __restrict__ W,
                                                      __bf16* __restrict__ WT,
                                                      int K, int Nn) {
    int i = blockIdx.x * 256 + threadIdx.x;
    if (i < K * Nn) {
        int k = i / Nn, n = i % Nn;
        WT[(size_t)n * K + k] = (__bf16)W[i];
    }
}

// ---------------- MFMA bf16 GEMM: C[M,256] = A[M,512] @ B[512,256] ----------
// A bf16 row-major, BT bf16 [256][512] (n-major), C bf16. 128x128 block tile,
// 4 waves in 2x2, each wave 64x64 via 4x4 grid of 16x16x32 MFMAs.

__global__ __launch_bounds__(256) void gemm1_mfma(const __bf16* __restrict__ Abf,
                                                  const __bf16* __restrict__ BTbf,
                                                  __bf16* __restrict__ Cbf, int M) {
    const int K = 512, Nn = 256;
    __shared__ __align__(16) __bf16 As[128 * 40];  // row stride 40 (pad 8) -> 2-way max
    __shared__ __align__(16) __bf16 Bs[128 * 40];
    const int tid = threadIdx.x;
    const int wave = tid >> 6, lane = tid & 63;
    const int wm = wave >> 1, wn = wave & 1;
    const int quad = lane >> 4, l16 = lane & 15;
    const int bm = blockIdx.x * 128, bn = blockIdx.y * 128;
    f32x4 acc[4][4] = {};
    for (int k0 = 0; k0 < K; k0 += 32) {
#pragma unroll
        for (int it = 0; it < 2; ++it) {
            int e = tid + it * 256;          // 0..511
            int row = e >> 2, ch = e & 3;    // 128 rows x 4 chunks of 8 bf16
            int gm = bm + row;
            bf16x8 v = {};
            if (gm < M) v = *(const bf16x8*)(Abf + (size_t)gm * K + k0 + ch * 8);
            *(bf16x8*)(As + row * 40 + ch * 8) = v;
            bf16x8 w = *(const bf16x8*)(BTbf + (size_t)(bn + row) * K + k0 + ch * 8);
            *(bf16x8*)(Bs + row * 40 + ch * 8) = w;
        }
        __syncthreads();
        bf16x8 a[4], b[4];
#pragma unroll
        for (int i = 0; i < 4; ++i)
            a[i] = *(bf16x8*)(As + (wm * 64 + i * 16 + l16) * 40 + quad * 8);
#pragma unroll
        for (int j = 0; j < 4; ++j)
            b[j] = *(bf16x8*)(Bs + (wn * 64 + j * 16 + l16) * 40 + quad * 8);
#pragma unroll
        for (int i = 0; i < 4; ++i)
#pragma unroll
            for (int j = 0; j < 4; ++j)
                acc[i][j] = __builtin_amdgcn_mfma_f32_16x16x32_bf16(a[i], b[j], acc[i][j], 0, 0, 0);
        __syncthreads();
    }
#pragma unroll
    for (int i = 0; i < 4; ++i)
#pragma unroll
        for (int j = 0; j < 4; ++j)
#pragma unroll
            for (int rr = 0; rr < 4; ++rr) {
                int row = bm + wm * 64 + i * 16 + quad * 4 + rr;
                int col = bn + wn * 64 + j * 16 + l16;
                if (row < M) Cbf[(size_t)row * Nn + col] = (__bf16)acc[i][j][rr];
            }
}

// ---------------- dense GEMM (fp32, 64x64 tile) for layers 2/3 -------------

__global__ __launch_bounds__(256) void gemm64(const float* __restrict__ A,
                                              const float* __restrict__ B,
                                              float* __restrict__ C,
                                              int M, int Nn, int K) {
    __shared__ float As[16][68];
    __shared__ float Bs[16][64];
    const int tid = threadIdx.x;
    const int tx = tid & 15, ty = tid >> 4;
    const int bm = blockIdx.x * 64, bn = blockIdx.y * 64;
    float acc[4][4] = {};
    for (int k0 = 0; k0 < K; k0 += 16) {
#pragma unroll
        for (int i = 0; i < 4; ++i) {
            int idx = tid + i * 256;
            int m = idx >> 4, kk = idx & 15;
            int gm = bm + m;
            As[kk][m] = (gm < M) ? A[(size_t)gm * K + k0 + kk] : 0.f;
            int kb = idx >> 6, n = idx & 63;
            Bs[kb][n] = B[(size_t)(k0 + kb) * Nn + bn + n];
        }
        __syncthreads();
#pragma unroll
        for (int kk = 0; kk < 16; ++kk) {
            float a[4], b[4];
#pragma unroll
            for (int i = 0; i < 4; ++i) a[i] = As[kk][ty * 4 + i];
#pragma unroll
            for (int j = 0; j < 4; ++j) b[j] = Bs[kk][tx * 4 + j];
#pragma unroll
            for (int i = 0; i < 4; ++i)
#pragma unroll
                for (int j = 0; j < 4; ++j) acc[i][j] = fmaf(a[i], b[j], acc[i][j]);
        }
        __syncthreads();
    }
#pragma unroll
    for (int i = 0; i < 4; ++i) {
        int row = bm + ty * 4 + i;
        if (row < M) {
            float4 v = make_float4(acc[i][0], acc[i][1], acc[i][2], acc[i][3]);
            *(float4*)(C + (size_t)row * Nn + bn + tx * 4) = v;
        }
    }
}

// ---------------- pull-mode SpMM ----------------
// 256-feature bf16-gather variant: one wave per dst node, lane holds 4 feats.

__global__ __launch_bounds__(256) void spmm256_bf16(const __bf16* __restrict__ h,
                                                    const int* __restrict__ rp,
                                                    const int* __restrict__ se,
                                                    const float* __restrict__ we,
                                                    const float* __restrict__ bias,
                                                    float* __restrict__ out, int n) {
    int node = blockIdx.x * 4 + (threadIdx.x >> 6);
    if (node >= n) return;
    int lane = threadIdx.x & 63;
    int e0 = rp[node], e1 = rp[node + 1];
    float4 acc = make_float4(0.f, 0.f, 0.f, 0.f);
    int e = e0;
    for (; e + 1 < e1; e += 2) {        // unroll x2 for MLP
        int s0 = se[e], s1 = se[e + 1];
        float w0 = we[e], w1 = we[e + 1];
        ushort4 v0 = *(const ushort4*)(h + (size_t)s0 * 256 + lane * 4);
        ushort4 v1 = *(const ushort4*)(h + (size_t)s1 * 256 + lane * 4);
        acc.x = fmaf(w0, bf2f(v0.x), acc.x); acc.y = fmaf(w0, bf2f(v0.y), acc.y);
        acc.z = fmaf(w0, bf2f(v0.z), acc.z); acc.w = fmaf(w0, bf2f(v0.w), acc.w);
        acc.x = fmaf(w1, bf2f(v1.x), acc.x); acc.y = fmaf(w1, bf2f(v1.y), acc.y);
        acc.z = fmaf(w1, bf2f(v1.z), acc.z); acc.w = fmaf(w1, bf2f(v1.w), acc.w);
    }
    if (e < e1) {
        int s0 = se[e];
        float w0 = we[e];
        ushort4 v0 = *(const ushort4*)(h + (size_t)s0 * 256 + lane * 4);
        acc.x = fmaf(w0, bf2f(v0.x), acc.x); acc.y = fmaf(w0, bf2f(v0.y), acc.y);
        acc.z = fmaf(w0, bf2f(v0.z), acc.z); acc.w = fmaf(w0, bf2f(v0.w), acc.w);
    }
    const float4 b = *(const float4*)(bias + lane * 4);
    acc.x = fmaxf(acc.x + b.x, 0.f);
    acc.y = fmaxf(acc.y + b.y, 0.f);
    acc.z = fmaxf(acc.z + b.z, 0.f);
    acc.w = fmaxf(acc.w + b.w, 0.f);
    *(float4*)(out + (size_t)node * 256 + lane * 4) = acc;
}

// 64-feature fp32 variant: lane == feature; optional fused log_softmax.
__global__ __launch_bounds__(256) void spmm64(const float* __restrict__ h,
                                              const int* __restrict__ rp,
                                              const int* __restrict__ se,
                                              const float* __restrict__ we,
                                              const float* __restrict__ bias,
                                              float* __restrict__ out, int n, int do_lse) {
    int node = blockIdx.x * 4 + (threadIdx.x >> 6);
    if (node >= n) return;
    int lane = threadIdx.x & 63;
    int e0 = rp[node], e1 = rp[node + 1];
    float acc = 0.f;
    for (int e = e0; e < e1; ++e) {
        acc = fmaf(we[e], h[(size_t)se[e] * 64 + lane], acc);
    }
    acc += bias[lane];
    if (do_lse) {
        float m = acc;
#pragma unroll
        for (int off = 32; off > 0; off >>= 1) m = fmaxf(m, __shfl_xor(m, off));
        float ex = __expf(acc - m);
        float s = ex;
#pragma unroll
        for (int off = 32; off > 0; off >>= 1) s += __shfl_xor(s, off);
        acc = acc - m - __logf(s);
    }
    out[(size_t)node * 64 + lane] = acc;
}

// ---------------------------------------------------------------------------

extern "C" void kernel_launch(void* const* d_in, const int* in_sizes, int n_in,
                              void* d_out, int out_size, void* d_ws, size_t ws_size,
                              hipStream_t stream) {
    const float* x  = (const float*)d_in[0];
    const int*   src = (const int*)d_in[1];
    const int*   dst = (const int*)d_in[2];
    const float* ew = (const float*)d_in[3];
    const float* W1 = (const float*)d_in[4];
    const float* b1 = (const float*)d_in[5];
    const float* W2 = (const float*)d_in[6];
    const float* b2 = (const float*)d_in[7];
    const float* W3 = (const float*)d_in[8];
    const float* r  = (const float*)d_in[9];

    const int N = in_sizes[0] / 512;   // 100000
    const int E = in_sizes[1];         // 3200000

    // ws layout (byte offsets); region A (N*1024 B) holds xb bf16[N*512],
    // later reused as h1 fp32[N*256]. Region B (N*512 B) holds h0b bf16[N*256],
    // later reused as h2in fp32[N*64] + g2 fp32[N*64]; h3in aliases h2in.
    char* ws = (char*)d_ws;
    __bf16* xb  = (__bf16*)ws;                       // N*512 bf16
    float*  h1  = (float*)ws;                        // N*256 f32 (after gemm1 done)
    char* regB  = ws + (size_t)N * 1024;
    __bf16* h0b = (__bf16*)regB;                     // N*256 bf16
    float* h2in = (float*)regB;                      // N*64 f32 (after spmm1 done)
    float* g2   = h2in + (size_t)N * 64;             // N*64 f32
    float* h3in = h2in;                              // alias (h2in dead)
    char* regC  = regB + (size_t)N * 512;
    __bf16* W1T = (__bf16*)regC;                     // 256*512 bf16 = 256 KiB
    char* regD  = regC + 512 * 256 * 2;
    int*   rp  = (int*)regD;                         // N+1
    int*   tmp = rp + (N + 1);                       // N
    int*   se  = tmp + N;                            // E
    float* we  = (float*)(se + E);                   // E

    // ---- CSR build ----
    hipMemsetAsync(tmp, 0, (size_t)N * sizeof(int), stream);
    count_edges<<<(E + 255) / 256, 256, 0, stream>>>(dst, tmp, E);
    scan_counts<<<1, 1024, 0, stream>>>(tmp, rp, N);
    hipMemsetAsync(tmp, 0, (size_t)N * sizeof(int), stream);
    scatter_edges<<<(E + 255) / 256, 256, 0, stream>>>(src, dst, ew, rp, tmp, se, we, E);

    // ---- casts for layer 1 ----
    long nx = (long)N * 512;
    cast_f32_bf16<<<(int)((nx / 4 + 255) / 256), 256, 0, stream>>>(x, xb, nx);
    cast_transpose<<<(512 * 256 + 255) / 256, 256, 0, stream>>>(W1, W1T, 512, 256);

    // ---- layer 1: MFMA gemm (bf16 out) + bf16-gather spmm ----
    dim3 g1((N + 127) / 128, 2);
    gemm1_mfma<<<g1, 256, 0, stream>>>(xb, W1T, h0b, N);
    spmm256_bf16<<<(N + 3) / 4, 256, 0, stream>>>(h0b, rp, se, we, b1, h1, N);

    // ---- layer 2 (fp32) ----
    dim3 g2d((N + 63) / 64, 1);
    gemm64<<<g2d, 256, 0, stream>>>(h1, W2, h2in, N, 64, 256);
    spmm64<<<(N + 3) / 4, 256, 0, stream>>>(h2in, rp, se, we, b2, g2, N, 0);

    // ---- layer 3 + fused log_softmax ----
    gemm64<<<g2d, 256, 0, stream>>>(g2, W3, h3in, N, 64, 64);
    spmm64<<<(N + 3) / 4, 256, 0, stream>>>(h3in, rp, se, we, r, (float*)d_out, N, 1);
}

// Round 3
// 1144.628 us; speedup vs baseline: 1.9337x; 1.4412x over previous
//
#include <hip/hip_runtime.h>
#include <math.h>

// ---------------------------------------------------------------------------
// StatusGCN restructured:
//   h0 = bf16(x @ W1)                       (MFMA)        [N,256] bf16
//   h1 = bf16(relu(spmm(h0) + b1))                        [N,256] bf16
//   g3 = bf16(h1 @ (W2@W3))                 (MFMA)        [N,64]  bf16
//   t1 = bf16(spmm(g3)); degw = rowsum(w)                 [N,64]  bf16
//   out = log_softmax(spmm(t1) + degw*(b2@W3) + r)        [N,64]  f32
// Identity used: spmm(X)@W == spmm(X@W);  spmm(X + 1*c) == spmm(X) + degw*c.
// spmm: pull-mode over dst-sorted CSR rebuilt each launch.
// ---------------------------------------------------------------------------

typedef __bf16 bf16x8 __attribute__((ext_vector_type(8)));
typedef __bf16 bf16x4 __attribute__((ext_vector_type(4)));
typedef float f32x4 __attribute__((ext_vector_type(4)));

// ---------------- CSR construction ----------------

__global__ void count_edges(const int* __restrict__ dst, int* __restrict__ cnt, int E) {
    int e = blockIdx.x * 256 + threadIdx.x;
    if (e < E) atomicAdd(&cnt[dst[e]], 1);
}

// two-level exclusive scan of cnt[n] -> rp[n] (+ rp[n]=total)
__global__ __launch_bounds__(256) void scan_block(const int* __restrict__ cnt,
                                                  int* __restrict__ rp,
                                                  int* __restrict__ bsum, int n) {
    __shared__ int sd[256];
    int i = blockIdx.x * 256 + threadIdx.x;
    int v = (i < n) ? cnt[i] : 0;
    sd[threadIdx.x] = v;
    __syncthreads();
    for (int off = 1; off < 256; off <<= 1) {
        int t = (threadIdx.x >= off) ? sd[threadIdx.x - off] : 0;
        __syncthreads();
        sd[threadIdx.x] += t;
        __syncthreads();
    }
    if (i < n) rp[i] = sd[threadIdx.x] - v;          // local exclusive
    if (threadIdx.x == 255) bsum[blockIdx.x] = sd[255];
}

__global__ __launch_bounds__(1024) void scan_bsum(int* __restrict__ bsum,
                                                  int* __restrict__ boff,
                                                  int nb, int* __restrict__ rp_end) {
    __shared__ int sd[1024];
    int tid = threadIdx.x;
    int v = (tid < nb) ? bsum[tid] : 0;
    sd[tid] = v;
    __syncthreads();
    for (int off = 1; off < 1024; off <<= 1) {
        int t = (tid >= off) ? sd[tid - off] : 0;
        __syncthreads();
        sd[tid] += t;
        __syncthreads();
    }
    if (tid < nb) boff[tid] = sd[tid] - v;           // exclusive
    if (tid == nb - 1) *rp_end = sd[tid];            // total
}

__global__ void add_boff(int* __restrict__ rp, const int* __restrict__ boff, int n) {
    int i = blockIdx.x * 256 + threadIdx.x;
    if (i < n) rp[i] += boff[blockIdx.x];
}

// scatter into packed (src, weight_bits) pairs
__global__ void scatter_edges(const int* __restrict__ src, const int* __restrict__ dst,
                              const float* __restrict__ ew, const int* __restrict__ rp,
                              int* __restrict__ tmp, int2* __restrict__ ep, int E) {
    int e = blockIdx.x * 256 + threadIdx.x;
    if (e < E) {
        int d = dst[e];
        int pos = rp[d] + atomicAdd(&tmp[d], 1);
        ep[pos] = make_int2(src[e], __float_as_int(ew[e]));
    }
}

// ---------------- casts / tiny precomputes ----------------

__global__ __launch_bounds__(256) void cast_f32_bf16(const float* __restrict__ in,
                                                     __bf16* __restrict__ out, long n) {
    long i = ((long)blockIdx.x * 256 + threadIdx.x) * 4;
    if (i + 3 < n) {
        float4 v = *(const float4*)(in + i);
        out[i]     = (__bf16)v.x;
        out[i + 1] = (__bf16)v.y;
        out[i + 2] = (__bf16)v.z;
        out[i + 3] = (__bf16)v.w;
    } else {
        for (long j = i; j < n; ++j) out[j] = (__bf16)in[j];
    }
}

// W [K, Nn] fp32 -> WT [Nn][K] bf16
__global__ __launch_bounds__(256) void cast_transpose(const float* __restrict__ W,
                                                      __bf16* __restrict__ WT,
                                                      int K, int Nn) {
    int i = blockIdx.x * 256 + threadIdx.x;
    if (i < K * Nn) {
        int k = i / Nn, n = i % Nn;
        WT[(size_t)n * K + k] = (__bf16)W[i];
    }
}

// W23T[n][k] = sum_j W2[k][j] * W3[j][n], k<256, n<64
__global__ __launch_bounds__(256) void make_w23t(const float* __restrict__ W2,
                                                 const float* __restrict__ W3,
                                                 __bf16* __restrict__ W23T) {
    int idx = blockIdx.x * 256 + threadIdx.x;   // 16384
    int n = idx & 63, k = idx >> 6;
    float s = 0.f;
    for (int j = 0; j < 64; ++j) s = fmaf(W2[k * 64 + j], W3[j * 64 + n], s);
    W23T[n * 256 + k] = (__bf16)s;
}

// c[n] = sum_j b2[j] * W3[j][n]
__global__ void make_c(const float* __restrict__ b2, const float* __restrict__ W3,
                       float* __restrict__ c) {
    int n = threadIdx.x;
    float s = 0.f;
    for (int j = 0; j < 64; ++j) s = fmaf(b2[j], W3[j * 64 + n], s);
    c[n] = s;
}

// ---------------- MFMA bf16 GEMM 1: C[M,256] = A[M,512] @ B[512,256] --------

__global__ __launch_bounds__(256) void gemm1_mfma(const __bf16* __restrict__ Abf,
                                                  const __bf16* __restrict__ BTbf,
                                                  __bf16* __restrict__ Cbf, int M) {
    const int K = 512, Nn = 256;
    __shared__ __align__(16) __bf16 As[128 * 40];
    __shared__ __align__(16) __bf16 Bs[128 * 40];
    const int tid = threadIdx.x;
    const int wave = tid >> 6, lane = tid & 63;
    const int wm = wave >> 1, wn = wave & 1;
    const int quad = lane >> 4, l16 = lane & 15;
    const int bm = blockIdx.x * 128, bn = blockIdx.y * 128;
    f32x4 acc[4][4] = {};
    for (int k0 = 0; k0 < K; k0 += 32) {
#pragma unroll
        for (int it = 0; it < 2; ++it) {
            int e = tid + it * 256;
            int row = e >> 2, ch = e & 3;
            int gm = bm + row;
            bf16x8 v = {};
            if (gm < M) v = *(const bf16x8*)(Abf + (size_t)gm * K + k0 + ch * 8);
            *(bf16x8*)(As + row * 40 + ch * 8) = v;
            bf16x8 w = *(const bf16x8*)(BTbf + (size_t)(bn + row) * K + k0 + ch * 8);
            *(bf16x8*)(Bs + row * 40 + ch * 8) = w;
        }
        __syncthreads();
        bf16x8 a[4], b[4];
#pragma unroll
        for (int i = 0; i < 4; ++i)
            a[i] = *(bf16x8*)(As + (wm * 64 + i * 16 + l16) * 40 + quad * 8);
#pragma unroll
        for (int j = 0; j < 4; ++j)
            b[j] = *(bf16x8*)(Bs + (wn * 64 + j * 16 + l16) * 40 + quad * 8);
#pragma unroll
        for (int i = 0; i < 4; ++i)
#pragma unroll
            for (int j = 0; j < 4; ++j)
                acc[i][j] = __builtin_amdgcn_mfma_f32_16x16x32_bf16(a[i], b[j], acc[i][j], 0, 0, 0);
        __syncthreads();
    }
#pragma unroll
    for (int i = 0; i < 4; ++i)
#pragma unroll
        for (int j = 0; j < 4; ++j)
#pragma unroll
            for (int rr = 0; rr < 4; ++rr) {
                int row = bm + wm * 64 + i * 16 + quad * 4 + rr;
                int col = bn + wn * 64 + j * 16 + l16;
                if (row < M) Cbf[(size_t)row * Nn + col] = (__bf16)acc[i][j][rr];
            }
}

// ---------------- MFMA bf16 GEMM 2: C[M,64] = A[M,256] @ B[256,64] ----------
// BT [64][256] resident in LDS; A staged per 32-k step. 128-row tile, 4 waves
// (wave = 32 rows).

__global__ __launch_bounds__(256) void gemm2_mfma(const __bf16* __restrict__ A,
                                                  const __bf16* __restrict__ BT,
                                                  __bf16* __restrict__ C, int M) {
    const int K = 256, Nn = 64;
    __shared__ __align__(16) __bf16 Bs[64 * 264];   // [n][k], pad 8
    __shared__ __align__(16) __bf16 As[128 * 40];   // [row][k32], pad 8
    const int tid = threadIdx.x;
    const int wave = tid >> 6, lane = tid & 63;
    const int quad = lane >> 4, l16 = lane & 15;
    const int bm = blockIdx.x * 128;
#pragma unroll
    for (int it = 0; it < 8; ++it) {                // 64*256 bf16 = 2048 x bf16x8
        int e = tid + it * 256;
        int row = e >> 5, ch = e & 31;
        *(bf16x8*)(Bs + row * 264 + ch * 8) = *(const bf16x8*)(BT + row * 256 + ch * 8);
    }
    f32x4 acc[2][4] = {};
    for (int k0 = 0; k0 < K; k0 += 32) {
#pragma unroll
        for (int it = 0; it < 2; ++it) {
            int e = tid + it * 256;
            int row = e >> 2, ch = e & 3;
            int gm = bm + row;
            bf16x8 v = {};
            if (gm < M) v = *(const bf16x8*)(A + (size_t)gm * K + k0 + ch * 8);
            *(bf16x8*)(As + row * 40 + ch * 8) = v;
        }
        __syncthreads();
        bf16x8 a[2], b[4];
#pragma unroll
        for (int i = 0; i < 2; ++i)
            a[i] = *(bf16x8*)(As + (wave * 32 + i * 16 + l16) * 40 + quad * 8);
#pragma unroll
        for (int j = 0; j < 4; ++j)
            b[j] = *(bf16x8*)(Bs + (j * 16 + l16) * 264 + k0 + quad * 8);
#pragma unroll
        for (int i = 0; i < 2; ++i)
#pragma unroll
            for (int j = 0; j < 4; ++j)
                acc[i][j] = __builtin_amdgcn_mfma_f32_16x16x32_bf16(a[i], b[j], acc[i][j], 0, 0, 0);
        __syncthreads();
    }
#pragma unroll
    for (int i = 0; i < 2; ++i)
#pragma unroll
        for (int j = 0; j < 4; ++j)
#pragma unroll
            for (int rr = 0; rr < 4; ++rr) {
                int row = bm + wave * 32 + i * 16 + quad * 4 + rr;
                int col = j * 16 + l16;
                if (row < M) C[(size_t)row * Nn + col] = (__bf16)acc[i][j][rr];
            }
}

// ---------------- pull-mode SpMM ----------------

__device__ __forceinline__ void fma4(float4& acc, float w, bf16x4 v) {
    acc.x = fmaf(w, (float)v[0], acc.x);
    acc.y = fmaf(w, (float)v[1], acc.y);
    acc.z = fmaf(w, (float)v[2], acc.z);
    acc.w = fmaf(w, (float)v[3], acc.w);
}

// 256-feature: one wave per node, lane holds 4 feats (bf16 in, bf16 out).
__global__ __launch_bounds__(256) void spmm256_bf16(const __bf16* __restrict__ h,
                                                    const int* __restrict__ rp,
                                                    const int2* __restrict__ ep,
                                                    const float* __restrict__ bias,
                                                    __bf16* __restrict__ out, int n) {
    int node = blockIdx.x * 4 + (threadIdx.x >> 6);
    if (node >= n) return;
    int lane = threadIdx.x & 63;
    int e0 = rp[node], e1 = rp[node + 1];
    float4 acc = make_float4(0.f, 0.f, 0.f, 0.f);
    int e = e0;
    for (; e + 3 < e1; e += 4) {
        int2 p0 = ep[e], p1 = ep[e + 1], p2 = ep[e + 2], p3 = ep[e + 3];
        bf16x4 v0 = *(const bf16x4*)(h + (size_t)p0.x * 256 + lane * 4);
        bf16x4 v1 = *(const bf16x4*)(h + (size_t)p1.x * 256 + lane * 4);
        bf16x4 v2 = *(const bf16x4*)(h + (size_t)p2.x * 256 + lane * 4);
        bf16x4 v3 = *(const bf16x4*)(h + (size_t)p3.x * 256 + lane * 4);
        fma4(acc, __int_as_float(p0.y), v0);
        fma4(acc, __int_as_float(p1.y), v1);
        fma4(acc, __int_as_float(p2.y), v2);
        fma4(acc, __int_as_float(p3.y), v3);
    }
    for (; e < e1; ++e) {
        int2 p = ep[e];
        bf16x4 v = *(const bf16x4*)(h + (size_t)p.x * 256 + lane * 4);
        fma4(acc, __int_as_float(p.y), v);
    }
    const float4 b = *(const float4*)(bias + lane * 4);
    bf16x4 o;
    o[0] = (__bf16)fmaxf(acc.x + b.x, 0.f);
    o[1] = (__bf16)fmaxf(acc.y + b.y, 0.f);
    o[2] = (__bf16)fmaxf(acc.z + b.z, 0.f);
    o[3] = (__bf16)fmaxf(acc.w + b.w, 0.f);
    *(bf16x4*)(out + (size_t)node * 256 + lane * 4) = o;
}

// 64-feature pass 1: t1 = spmm(g3) (bf16 in/out), also degw = rowsum(w).
__global__ __launch_bounds__(256) void spmm64_a(const __bf16* __restrict__ h,
                                                const int* __restrict__ rp,
                                                const int2* __restrict__ ep,
                                                __bf16* __restrict__ out,
                                                float* __restrict__ degw, int n) {
    int node = blockIdx.x * 4 + (threadIdx.x >> 6);
    if (node >= n) return;
    int lane = threadIdx.x & 63;
    int e0 = rp[node], e1 = rp[node + 1];
    float acc = 0.f, ws = 0.f;
    int e = e0;
    for (; e + 3 < e1; e += 4) {
        int2 p0 = ep[e], p1 = ep[e + 1], p2 = ep[e + 2], p3 = ep[e + 3];
        float v0 = (float)h[(size_t)p0.x * 64 + lane];
        float v1 = (float)h[(size_t)p1.x * 64 + lane];
        float v2 = (float)h[(size_t)p2.x * 64 + lane];
        float v3 = (float)h[(size_t)p3.x * 64 + lane];
        float w0 = __int_as_float(p0.y), w1 = __int_as_float(p1.y);
        float w2 = __int_as_float(p2.y), w3 = __int_as_float(p3.y);
        acc = fmaf(w0, v0, acc); acc = fmaf(w1, v1, acc);
        acc = fmaf(w2, v2, acc); acc = fmaf(w3, v3, acc);
        ws += w0 + w1 + w2 + w3;
    }
    for (; e < e1; ++e) {
        int2 p = ep[e];
        float w = __int_as_float(p.y);
        acc = fmaf(w, (float)h[(size_t)p.x * 64 + lane], acc);
        ws += w;
    }
    if (lane == 0) degw[node] = ws;
    out[(size_t)node * 64 + lane] = (__bf16)acc;
}

// 64-feature pass 2: out = log_softmax(spmm(t1) + degw*c + r), fp32 out.
__global__ __launch_bounds__(256) void spmm64_b(const __bf16* __restrict__ h,
                                                const int* __restrict__ rp,
                                                const int2* __restrict__ ep,
                                                const float* __restrict__ degw,
                                                const float* __restrict__ c,
                                                const float* __restrict__ r,
                                                float* __restrict__ out, int n) {
    int node = blockIdx.x * 4 + (threadIdx.x >> 6);
    if (node >= n) return;
    int lane = threadIdx.x & 63;
    int e0 = rp[node], e1 = rp[node + 1];
    float acc = 0.f;
    int e = e0;
    for (; e + 3 < e1; e += 4) {
        int2 p0 = ep[e], p1 = ep[e + 1], p2 = ep[e + 2], p3 = ep[e + 3];
        float v0 = (float)h[(size_t)p0.x * 64 + lane];
        float v1 = (float)h[(size_t)p1.x * 64 + lane];
        float v2 = (float)h[(size_t)p2.x * 64 + lane];
        float v3 = (float)h[(size_t)p3.x * 64 + lane];
        acc = fmaf(__int_as_float(p0.y), v0, acc);
        acc = fmaf(__int_as_float(p1.y), v1, acc);
        acc = fmaf(__int_as_float(p2.y), v2, acc);
        acc = fmaf(__int_as_float(p3.y), v3, acc);
    }
    for (; e < e1; ++e) {
        int2 p = ep[e];
        acc = fmaf(__int_as_float(p.y), (float)h[(size_t)p.x * 64 + lane], acc);
    }
    acc += degw[node] * c[lane] + r[lane];
    float m = acc;
#pragma unroll
    for (int off = 32; off > 0; off >>= 1) m = fmaxf(m, __shfl_xor(m, off));
    float ex = __expf(acc - m);
    float s = ex;
#pragma unroll
    for (int off = 32; off > 0; off >>= 1) s += __shfl_xor(s, off);
    out[(size_t)node * 64 + lane] = acc - m - __logf(s);
}

// ---------------------------------------------------------------------------

extern "C" void kernel_launch(void* const* d_in, const int* in_sizes, int n_in,
                              void* d_out, int out_size, void* d_ws, size_t ws_size,
                              hipStream_t stream) {
    const float* x   = (const float*)d_in[0];
    const int*   src = (const int*)d_in[1];
    const int*   dst = (const int*)d_in[2];
    const float* ew  = (const float*)d_in[3];
    const float* W1  = (const float*)d_in[4];
    const float* b1  = (const float*)d_in[5];
    const float* W2  = (const float*)d_in[6];
    const float* b2  = (const float*)d_in[7];
    const float* W3  = (const float*)d_in[8];
    const float* r   = (const float*)d_in[9];

    const int N = in_sizes[0] / 512;   // 100000
    const int E = in_sizes[1];         // 3200000
    const int nb = (N + 255) / 256;    // scan blocks

    // ---- workspace layout ----
    char* ws = (char*)d_ws;
    // region A: xb bf16[N*512]  ->  h1 bf16[N*256]
    __bf16* xb = (__bf16*)ws;
    __bf16* h1 = (__bf16*)ws;
    char* regB = ws + (size_t)N * 1024;
    // region B: h0b bf16[N*256] -> { g3 bf16[N*64], t1 bf16[N*64], degw f32[N] }
    __bf16* h0b  = (__bf16*)regB;
    __bf16* g3   = (__bf16*)regB;
    __bf16* t1   = (__bf16*)(regB + (size_t)N * 128);
    float*  degw = (float*)(regB + (size_t)N * 256);
    char* regC = regB + (size_t)N * 512;
    __bf16* W1T  = (__bf16*)regC;                        // 512*256 bf16
    __bf16* W23T = (__bf16*)(regC + 512 * 256 * 2);      // 64*256 bf16
    float*  cvec = (float*)(regC + 512 * 256 * 2 + 64 * 256 * 2);
    int* bsum = (int*)(regC + 512 * 256 * 2 + 64 * 256 * 2 + 256);
    int* boff = bsum + 1024;
    char* regD = regC + 512 * 1024;
    int*  rp  = (int*)regD;                              // N+1
    int*  tmp = rp + (N + 1);                            // N
    int2* ep  = (int2*)(tmp + N);                        // E pairs

    // ---- CSR build ----
    hipMemsetAsync(tmp, 0, (size_t)N * sizeof(int), stream);
    count_edges<<<(E + 255) / 256, 256, 0, stream>>>(dst, tmp, E);
    scan_block<<<nb, 256, 0, stream>>>(tmp, rp, bsum, N);
    scan_bsum<<<1, 1024, 0, stream>>>(bsum, boff, nb, rp + N);
    add_boff<<<nb, 256, 0, stream>>>(rp, boff, N);
    hipMemsetAsync(tmp, 0, (size_t)N * sizeof(int), stream);
    scatter_edges<<<(E + 255) / 256, 256, 0, stream>>>(src, dst, ew, rp, tmp, ep, E);

    // ---- precomputes ----
    long nx = (long)N * 512;
    cast_f32_bf16<<<(int)((nx / 4 + 255) / 256), 256, 0, stream>>>(x, xb, nx);
    cast_transpose<<<(512 * 256 + 255) / 256, 256, 0, stream>>>(W1, W1T, 512, 256);
    make_w23t<<<64, 256, 0, stream>>>(W2, W3, W23T);
    make_c<<<1, 64, 0, stream>>>(b2, W3, cvec);

    // ---- layer 1 ----
    dim3 g1((N + 127) / 128, 2);
    gemm1_mfma<<<g1, 256, 0, stream>>>(xb, W1T, h0b, N);
    spmm256_bf16<<<(N + 3) / 4, 256, 0, stream>>>(h0b, rp, ep, b1, h1, N);

    // ---- fused layers 2+3 ----
    gemm2_mfma<<<(N + 127) / 128, 256, 0, stream>>>(h1, W23T, g3, N);
    spmm64_a<<<(N + 3) / 4, 256, 0, stream>>>(g3, rp, ep, t1, degw, N);
    spmm64_b<<<(N + 3) / 4, 256, 0, stream>>>(t1, rp, ep, degw, cvec, r, (float*)d_out, N);
}

// Round 4
// 1122.923 us; speedup vs baseline: 1.9711x; 1.0193x over previous
//
#include <hip/hip_runtime.h>
#include <math.h>

// ---------------------------------------------------------------------------
// StatusGCN restructured:
//   h0 = bf16(x @ W1)                 (MFMA, fp32 A cast in staging) [N,256]
//   h1 = bf16(relu(spmm(h0) + b1))                                  [N,256]
//   g3 = bf16(h1 @ (W2@W3))           (MFMA)                        [N,64]
//   t1 = bf16(spmm(g3)); degw = rowsum(w)                           [N,64]
//   out = log_softmax(spmm(t1) + degw*(b2@W3) + r)                  [N,64] f32
// Identities: spmm(X)@W == spmm(X@W);  spmm(X + 1*c) == spmm(X) + degw*c.
// spmm: pull-mode over dst-sorted CSR rebuilt each launch; lanes are split
// (edge-group x feature-chunk) for 16B/lane gathers and deep MLP.
// ---------------------------------------------------------------------------

typedef __bf16 bf16x8 __attribute__((ext_vector_type(8)));
typedef __bf16 bf16x4 __attribute__((ext_vector_type(4)));
typedef float f32x4 __attribute__((ext_vector_type(4)));

// ---------------- CSR construction ----------------

__global__ void count_edges(const int* __restrict__ dst, int* __restrict__ cnt, int E) {
    int e = blockIdx.x * 256 + threadIdx.x;
    if (e < E) atomicAdd(&cnt[dst[e]], 1);
}

__global__ __launch_bounds__(256) void scan_block(const int* __restrict__ cnt,
                                                  int* __restrict__ rp,
                                                  int* __restrict__ bsum, int n) {
    __shared__ int sd[256];
    int i = blockIdx.x * 256 + threadIdx.x;
    int v = (i < n) ? cnt[i] : 0;
    sd[threadIdx.x] = v;
    __syncthreads();
    for (int off = 1; off < 256; off <<= 1) {
        int t = (threadIdx.x >= off) ? sd[threadIdx.x - off] : 0;
        __syncthreads();
        sd[threadIdx.x] += t;
        __syncthreads();
    }
    if (i < n) rp[i] = sd[threadIdx.x] - v;
    if (threadIdx.x == 255) bsum[blockIdx.x] = sd[255];
}

__global__ __launch_bounds__(1024) void scan_bsum(int* __restrict__ bsum,
                                                  int* __restrict__ boff,
                                                  int nb, int* __restrict__ rp_end) {
    __shared__ int sd[1024];
    int tid = threadIdx.x;
    int v = (tid < nb) ? bsum[tid] : 0;
    sd[tid] = v;
    __syncthreads();
    for (int off = 1; off < 1024; off <<= 1) {
        int t = (tid >= off) ? sd[tid - off] : 0;
        __syncthreads();
        sd[tid] += t;
        __syncthreads();
    }
    if (tid < nb) boff[tid] = sd[tid] - v;
    if (tid == nb - 1) *rp_end = sd[tid];
}

__global__ void add_boff(int* __restrict__ rp, const int* __restrict__ boff, int n) {
    int i = blockIdx.x * 256 + threadIdx.x;
    if (i < n) rp[i] += boff[blockIdx.x];
}

__global__ void scatter_edges(const int* __restrict__ src, const int* __restrict__ dst,
                              const float* __restrict__ ew, const int* __restrict__ rp,
                              int* __restrict__ tmp, int2* __restrict__ ep, int E) {
    int e = blockIdx.x * 256 + threadIdx.x;
    if (e < E) {
        int d = dst[e];
        int pos = rp[d] + atomicAdd(&tmp[d], 1);
        ep[pos] = make_int2(src[e], __float_as_int(ew[e]));
    }
}

// ---------------- tiny precomputes ----------------

// W [K, Nn] fp32 -> WT [Nn][K] bf16
__global__ __launch_bounds__(256) void cast_transpose(const float* __restrict__ W,
                                                      __bf16* __restrict__ WT,
                                                      int K, int Nn) {
    int i = blockIdx.x * 256 + threadIdx.x;
    if (i < K * Nn) {
        int k = i / Nn, n = i % Nn;
        WT[(size_t)n * K + k] = (__bf16)W[i];
    }
}

// W23T[n][k] = sum_j W2[k][j] * W3[j][n], k<256, n<64
__global__ __launch_bounds__(256) void make_w23t(const float* __restrict__ W2,
                                                 const float* __restrict__ W3,
                                                 __bf16* __restrict__ W23T) {
    int idx = blockIdx.x * 256 + threadIdx.x;
    int n = idx & 63, k = idx >> 6;
    float s = 0.f;
    for (int j = 0; j < 64; ++j) s = fmaf(W2[k * 64 + j], W3[j * 64 + n], s);
    W23T[n * 256 + k] = (__bf16)s;
}

// c[n] = sum_j b2[j] * W3[j][n]
__global__ void make_c(const float* __restrict__ b2, const float* __restrict__ W3,
                       float* __restrict__ c) {
    int n = threadIdx.x;
    float s = 0.f;
    for (int j = 0; j < 64; ++j) s = fmaf(b2[j], W3[j * 64 + n], s);
    c[n] = s;
}

// ------- MFMA GEMM 1: C[M,256] = bf16(A_f32[M,512]) @ W1[512,256] -----------
// Single pass over x (fp32, cast during LDS staging). 128-row tile, 4 waves
// in 2x2; wave computes 64x128 via 4x8 grid of 16x16x32 MFMAs.

__global__ __launch_bounds__(256) void gemm1_fused(const float* __restrict__ A,
                                                   const __bf16* __restrict__ BT,
                                                   __bf16* __restrict__ C, int M) {
    const int K = 512;
    __shared__ __align__(16) __bf16 As[128 * 40];
    __shared__ __align__(16) __bf16 Bs[256 * 40];
    const int tid = threadIdx.x;
    const int wave = tid >> 6, lane = tid & 63;
    const int wm = wave >> 1, wn = wave & 1;
    const int quad = lane >> 4, l16 = lane & 15;
    const int bm = blockIdx.x * 128;
    f32x4 acc[4][8] = {};
    for (int k0 = 0; k0 < K; k0 += 32) {
#pragma unroll
        for (int it = 0; it < 4; ++it) {           // A: 128 rows x 32 k fp32
            int idx = tid + it * 256;              // 0..1023 float4s
            int row = idx >> 3, ch = idx & 7;
            int gm = bm + row;
            float4 v = (gm < M) ? *(const float4*)(A + (size_t)gm * K + k0 + ch * 4)
                                : make_float4(0.f, 0.f, 0.f, 0.f);
            bf16x4 o;
            o[0] = (__bf16)v.x; o[1] = (__bf16)v.y; o[2] = (__bf16)v.z; o[3] = (__bf16)v.w;
            *(bf16x4*)(As + row * 40 + ch * 4) = o;
        }
#pragma unroll
        for (int it = 0; it < 4; ++it) {           // B: 256 rows x 32 k bf16
            int idx = tid + it * 256;              // 0..1023 bf16x8s
            int row = idx >> 2, ch = idx & 3;
            *(bf16x8*)(Bs + row * 40 + ch * 8) =
                *(const bf16x8*)(BT + (size_t)row * K + k0 + ch * 8);
        }
        __syncthreads();
        bf16x8 a[4], b[8];
#pragma unroll
        for (int i = 0; i < 4; ++i)
            a[i] = *(bf16x8*)(As + (wm * 64 + i * 16 + l16) * 40 + quad * 8);
#pragma unroll
        for (int j = 0; j < 8; ++j)
            b[j] = *(bf16x8*)(Bs + (wn * 128 + j * 16 + l16) * 40 + quad * 8);
#pragma unroll
        for (int i = 0; i < 4; ++i)
#pragma unroll
            for (int j = 0; j < 8; ++j)
                acc[i][j] = __builtin_amdgcn_mfma_f32_16x16x32_bf16(a[i], b[j], acc[i][j], 0, 0, 0);
        __syncthreads();
    }
#pragma unroll
    for (int i = 0; i < 4; ++i)
#pragma unroll
        for (int j = 0; j < 8; ++j)
#pragma unroll
            for (int rr = 0; rr < 4; ++rr) {
                int row = bm + wm * 64 + i * 16 + quad * 4 + rr;
                int col = wn * 128 + j * 16 + l16;
                if (row < M) C[(size_t)row * 256 + col] = (__bf16)acc[i][j][rr];
            }
}

// ---------------- MFMA GEMM 2: C[M,64] = A[M,256] @ B[256,64] ---------------

__global__ __launch_bounds__(256) void gemm2_mfma(const __bf16* __restrict__ A,
                                                  const __bf16* __restrict__ BT,
                                                  __bf16* __restrict__ C, int M) {
    const int K = 256, Nn = 64;
    __shared__ __align__(16) __bf16 Bs[64 * 264];
    __shared__ __align__(16) __bf16 As[128 * 40];
    const int tid = threadIdx.x;
    const int wave = tid >> 6, lane = tid & 63;
    const int quad = lane >> 4, l16 = lane & 15;
    const int bm = blockIdx.x * 128;
#pragma unroll
    for (int it = 0; it < 8; ++it) {
        int e = tid + it * 256;
        int row = e >> 5, ch = e & 31;
        *(bf16x8*)(Bs + row * 264 + ch * 8) = *(const bf16x8*)(BT + row * 256 + ch * 8);
    }
    f32x4 acc[2][4] = {};
    for (int k0 = 0; k0 < K; k0 += 32) {
#pragma unroll
        for (int it = 0; it < 2; ++it) {
            int e = tid + it * 256;
            int row = e >> 2, ch = e & 3;
            int gm = bm + row;
            bf16x8 v = {};
            if (gm < M) v = *(const bf16x8*)(A + (size_t)gm * K + k0 + ch * 8);
            *(bf16x8*)(As + row * 40 + ch * 8) = v;
        }
        __syncthreads();
        bf16x8 a[2], b[4];
#pragma unroll
        for (int i = 0; i < 2; ++i)
            a[i] = *(bf16x8*)(As + (wave * 32 + i * 16 + l16) * 40 + quad * 8);
#pragma unroll
        for (int j = 0; j < 4; ++j)
            b[j] = *(bf16x8*)(Bs + (j * 16 + l16) * 264 + k0 + quad * 8);
#pragma unroll
        for (int i = 0; i < 2; ++i)
#pragma unroll
            for (int j = 0; j < 4; ++j)
                acc[i][j] = __builtin_amdgcn_mfma_f32_16x16x32_bf16(a[i], b[j], acc[i][j], 0, 0, 0);
        __syncthreads();
    }
#pragma unroll
    for (int i = 0; i < 2; ++i)
#pragma unroll
        for (int j = 0; j < 4; ++j)
#pragma unroll
            for (int rr = 0; rr < 4; ++rr) {
                int row = bm + wave * 32 + i * 16 + quad * 4 + rr;
                int col = j * 16 + l16;
                if (row < M) C[(size_t)row * Nn + col] = (__bf16)acc[i][j][rr];
            }
}

// ---------------- pull-mode SpMM ----------------

// 256-feat: wave per node; half=lane>>5 picks edge slot, c=lane&31 picks 16B
// chunk of the 512B row. 8 edges per iteration -> 4x16B gathers in flight.
__global__ __launch_bounds__(256) void spmm256_bf16(const __bf16* __restrict__ h,
                                                    const int* __restrict__ rp,
                                                    const int2* __restrict__ ep,
                                                    const float* __restrict__ bias,
                                                    __bf16* __restrict__ out, int n) {
    int node = blockIdx.x * 4 + (threadIdx.x >> 6);
    if (node >= n) return;
    int lane = threadIdx.x & 63;
    int half = lane >> 5, c = lane & 31;
    int e0 = rp[node], e1 = rp[node + 1];
    float acc[8] = {};
    for (int e = e0; e < e1; e += 8) {
#pragma unroll
        for (int u = 0; u < 4; ++u) {
            int ee = e + u * 2 + half;
            int cl = min(ee, e1 - 1);
            int2 p = ep[cl];
            float w = (ee < e1) ? __int_as_float(p.y) : 0.f;
            bf16x8 v = *(const bf16x8*)(h + (size_t)p.x * 256 + c * 8);
#pragma unroll
            for (int i = 0; i < 8; ++i) acc[i] = fmaf(w, (float)v[i], acc[i]);
        }
    }
#pragma unroll
    for (int i = 0; i < 8; ++i) acc[i] += __shfl_xor(acc[i], 32);
    if (half == 0) {
        float4 b0 = *(const float4*)(bias + c * 8);
        float4 b1 = *(const float4*)(bias + c * 8 + 4);
        bf16x8 o;
        o[0] = (__bf16)fmaxf(acc[0] + b0.x, 0.f);
        o[1] = (__bf16)fmaxf(acc[1] + b0.y, 0.f);
        o[2] = (__bf16)fmaxf(acc[2] + b0.z, 0.f);
        o[3] = (__bf16)fmaxf(acc[3] + b0.w, 0.f);
        o[4] = (__bf16)fmaxf(acc[4] + b1.x, 0.f);
        o[5] = (__bf16)fmaxf(acc[5] + b1.y, 0.f);
        o[6] = (__bf16)fmaxf(acc[6] + b1.z, 0.f);
        o[7] = (__bf16)fmaxf(acc[7] + b1.w, 0.f);
        *(bf16x8*)(out + (size_t)node * 256 + c * 8) = o;
    }
}

// 64-feat pass 1: t1 = spmm(g3) bf16, degw = rowsum(w).
// g=lane>>3 picks one of 8 parallel edges, c=lane&7 picks 16B chunk (8 feats).
__global__ __launch_bounds__(256) void spmm64_a(const __bf16* __restrict__ h,
                                                const int* __restrict__ rp,
                                                const int2* __restrict__ ep,
                                                __bf16* __restrict__ out,
                                                float* __restrict__ degw, int n) {
    int node = blockIdx.x * 4 + (threadIdx.x >> 6);
    if (node >= n) return;
    int lane = threadIdx.x & 63;
    int g = lane >> 3, c = lane & 7;
    int e0 = rp[node], e1 = rp[node + 1];
    float acc[8] = {};
    float ws = 0.f;
    for (int e = e0; e < e1; e += 16) {
#pragma unroll
        for (int u = 0; u < 2; ++u) {
            int ee = e + u * 8 + g;
            int cl = min(ee, e1 - 1);
            int2 p = ep[cl];
            float w = (ee < e1) ? __int_as_float(p.y) : 0.f;
            bf16x8 v = *(const bf16x8*)(h + (size_t)p.x * 64 + c * 8);
#pragma unroll
            for (int i = 0; i < 8; ++i) acc[i] = fmaf(w, (float)v[i], acc[i]);
            ws += w;
        }
    }
#pragma unroll
    for (int off = 8; off <= 32; off <<= 1) {
        ws += __shfl_xor(ws, off);
#pragma unroll
        for (int i = 0; i < 8; ++i) acc[i] += __shfl_xor(acc[i], off);
    }
    if (lane == 0) degw[node] = ws;
    if (g == 0) {
        bf16x8 o;
#pragma unroll
        for (int i = 0; i < 8; ++i) o[i] = (__bf16)acc[i];
        *(bf16x8*)(out + (size_t)node * 64 + c * 8) = o;
    }
}

// 64-feat pass 2: out = log_softmax(spmm(t1) + degw*cvec + r), fp32.
__global__ __launch_bounds__(256) void spmm64_b(const __bf16* __restrict__ h,
                                                const int* __restrict__ rp,
                                                const int2* __restrict__ ep,
                                                const float* __restrict__ degw,
                                                const float* __restrict__ cvec,
                                                const float* __restrict__ r,
                                                float* __restrict__ out, int n) {
    int node = blockIdx.x * 4 + (threadIdx.x >> 6);
    if (node >= n) return;
    int lane = threadIdx.x & 63;
    int g = lane >> 3, c = lane & 7;
    int e0 = rp[node], e1 = rp[node + 1];
    float acc[8] = {};
    for (int e = e0; e < e1; e += 16) {
#pragma unroll
        for (int u = 0; u < 2; ++u) {
            int ee = e + u * 8 + g;
            int cl = min(ee, e1 - 1);
            int2 p = ep[cl];
            float w = (ee < e1) ? __int_as_float(p.y) : 0.f;
            bf16x8 v = *(const bf16x8*)(h + (size_t)p.x * 64 + c * 8);
#pragma unroll
            for (int i = 0; i < 8; ++i) acc[i] = fmaf(w, (float)v[i], acc[i]);
        }
    }
#pragma unroll
    for (int off = 8; off <= 32; off <<= 1)
#pragma unroll
        for (int i = 0; i < 8; ++i) acc[i] += __shfl_xor(acc[i], off);
    // every lane now holds full sums for features c*8..c*8+7
    float dw = degw[node];
    float4 c0 = *(const float4*)(cvec + c * 8), c1 = *(const float4*)(cvec + c * 8 + 4);
    float4 r0 = *(const float4*)(r + c * 8),    r1 = *(const float4*)(r + c * 8 + 4);
    float v[8];
    v[0] = acc[0] + dw * c0.x + r0.x; v[1] = acc[1] + dw * c0.y + r0.y;
    v[2] = acc[2] + dw * c0.z + r0.z; v[3] = acc[3] + dw * c0.w + r0.w;
    v[4] = acc[4] + dw * c1.x + r1.x; v[5] = acc[5] + dw * c1.y + r1.y;
    v[6] = acc[6] + dw * c1.z + r1.z; v[7] = acc[7] + dw * c1.w + r1.w;
    float m = v[0];
#pragma unroll
    for (int i = 1; i < 8; ++i) m = fmaxf(m, v[i]);
#pragma unroll
    for (int off = 1; off <= 4; off <<= 1) m = fmaxf(m, __shfl_xor(m, off));
    float s = 0.f;
#pragma unroll
    for (int i = 0; i < 8; ++i) s += __expf(v[i] - m);
#pragma unroll
    for (int off = 1; off <= 4; off <<= 1) s += __shfl_xor(s, off);
    float ls = m + __logf(s);
    if (g == 0) {
        float4 o0 = make_float4(v[0] - ls, v[1] - ls, v[2] - ls, v[3] - ls);
        float4 o1 = make_float4(v[4] - ls, v[5] - ls, v[6] - ls, v[7] - ls);
        *(float4*)(out + (size_t)node * 64 + c * 8) = o0;
        *(float4*)(out + (size_t)node * 64 + c * 8 + 4) = o1;
    }
}

// ---------------------------------------------------------------------------

extern "C" void kernel_launch(void* const* d_in, const int* in_sizes, int n_in,
                              void* d_out, int out_size, void* d_ws, size_t ws_size,
                              hipStream_t stream) {
    const float* x   = (const float*)d_in[0];
    const int*   src = (const int*)d_in[1];
    const int*   dst = (const int*)d_in[2];
    const float* ew  = (const float*)d_in[3];
    const float* W1  = (const float*)d_in[4];
    const float* b1  = (const float*)d_in[5];
    const float* W2  = (const float*)d_in[6];
    const float* b2  = (const float*)d_in[7];
    const float* W3  = (const float*)d_in[8];
    const float* r   = (const float*)d_in[9];

    const int N = in_sizes[0] / 512;   // 100000
    const int E = in_sizes[1];         // 3200000
    const int nb = (N + 255) / 256;

    // ---- workspace layout ----
    char* ws = (char*)d_ws;
    __bf16* h1 = (__bf16*)ws;                            // N*256 bf16 @ 0
    char* regB = ws + (size_t)N * 512;
    __bf16* h0b  = (__bf16*)regB;                        // N*256 bf16
    __bf16* g3   = (__bf16*)regB;                        // reuse after spmm256
    __bf16* t1   = (__bf16*)(regB + (size_t)N * 128);
    float*  degw = (float*)(regB + (size_t)N * 256);
    char* regC = regB + (size_t)N * 512;
    __bf16* W1T  = (__bf16*)regC;                        // 512*256 bf16
    __bf16* W23T = (__bf16*)(regC + 512 * 256 * 2);      // 64*256 bf16
    float*  cvec = (float*)(regC + 512 * 256 * 2 + 64 * 256 * 2);
    int* bsum = (int*)(regC + 512 * 256 * 2 + 64 * 256 * 2 + 256);
    int* boff = bsum + 1024;
    char* regD = regC + 512 * 1024;
    int*  rp  = (int*)regD;                              // N+1
    int*  tmp = rp + (N + 1);                            // N
    int2* ep  = (int2*)(tmp + N);                        // E pairs

    // ---- CSR build ----
    hipMemsetAsync(tmp, 0, (size_t)N * sizeof(int), stream);
    count_edges<<<(E + 255) / 256, 256, 0, stream>>>(dst, tmp, E);
    scan_block<<<nb, 256, 0, stream>>>(tmp, rp, bsum, N);
    scan_bsum<<<1, 1024, 0, stream>>>(bsum, boff, nb, rp + N);
    add_boff<<<nb, 256, 0, stream>>>(rp, boff, N);
    hipMemsetAsync(tmp, 0, (size_t)N * sizeof(int), stream);
    scatter_edges<<<(E + 255) / 256, 256, 0, stream>>>(src, dst, ew, rp, tmp, ep, E);

    // ---- precomputes ----
    cast_transpose<<<(512 * 256 + 255) / 256, 256, 0, stream>>>(W1, W1T, 512, 256);
    make_w23t<<<64, 256, 0, stream>>>(W2, W3, W23T);
    make_c<<<1, 64, 0, stream>>>(b2, W3, cvec);

    // ---- layer 1 ----
    gemm1_fused<<<(N + 127) / 128, 256, 0, stream>>>(x, W1T, h0b, N);
    spmm256_bf16<<<(N + 3) / 4, 256, 0, stream>>>(h0b, rp, ep, b1, h1, N);

    // ---- fused layers 2+3 ----
    gemm2_mfma<<<(N + 127) / 128, 256, 0, stream>>>(h1, W23T, g3, N);
    spmm64_a<<<(N + 3) / 4, 256, 0, stream>>>(g3, rp, ep, t1, degw, N);
    spmm64_b<<<(N + 3) / 4, 256, 0, stream>>>(t1, rp, ep, degw, cvec, r, (float*)d_out, N);
}

// Round 5
// 1062.900 us; speedup vs baseline: 2.0824x; 1.0565x over previous
//
#include <hip/hip_runtime.h>
#include <math.h>

// ---------------------------------------------------------------------------
// StatusGCN restructured:
//   h0 = bf16(x @ W1)                 (MFMA, fp32 A cast in staging) [N,256]
//   h1 = bf16(relu(spmm(h0) + b1))                                  [N,256]
//   g3 = bf16(h1 @ (W2@W3))           (MFMA)                        [N,64]
//   t1 = bf16(spmm(g3)); degw = rowsum(w)                           [N,64]
//   out = log_softmax(spmm(t1) + degw*(b2@W3) + r)                  [N,64] f32
// Identities: spmm(X)@W == spmm(X@W);  spmm(X + 1*c) == spmm(X) + degw*c.
// spmm: pull-mode over dst-sorted CSR rebuilt each launch; lanes are split
// (edge-group x feature-chunk) for 16B/lane gathers and deep MLP.
// NOTE (r4 post-mortem): keep per-wave MFMA tile at 64x64 (acc[4][4]=64 AGPR).
// acc[4][8] put wave reg total >256 on the unified VGPR/AGPR file -> 1
// wave/SIMD -> 9.5% occupancy, 240us. Do not widen the accumulator again.
// ---------------------------------------------------------------------------

typedef __bf16 bf16x8 __attribute__((ext_vector_type(8)));
typedef __bf16 bf16x4 __attribute__((ext_vector_type(4)));
typedef float f32x4 __attribute__((ext_vector_type(4)));

// ---------------- CSR construction ----------------

__global__ void count_edges(const int* __restrict__ dst, int* __restrict__ cnt, int E) {
    int e = blockIdx.x * 256 + threadIdx.x;
    if (e < E) atomicAdd(&cnt[dst[e]], 1);
}

__global__ __launch_bounds__(256) void scan_block(const int* __restrict__ cnt,
                                                  int* __restrict__ rp,
                                                  int* __restrict__ bsum, int n) {
    __shared__ int sd[256];
    int i = blockIdx.x * 256 + threadIdx.x;
    int v = (i < n) ? cnt[i] : 0;
    sd[threadIdx.x] = v;
    __syncthreads();
    for (int off = 1; off < 256; off <<= 1) {
        int t = (threadIdx.x >= off) ? sd[threadIdx.x - off] : 0;
        __syncthreads();
        sd[threadIdx.x] += t;
        __syncthreads();
    }
    if (i < n) rp[i] = sd[threadIdx.x] - v;
    if (threadIdx.x == 255) bsum[blockIdx.x] = sd[255];
}

__global__ __launch_bounds__(1024) void scan_bsum(int* __restrict__ bsum,
                                                  int* __restrict__ boff,
                                                  int nb, int* __restrict__ rp_end) {
    __shared__ int sd[1024];
    int tid = threadIdx.x;
    int v = (tid < nb) ? bsum[tid] : 0;
    sd[tid] = v;
    __syncthreads();
    for (int off = 1; off < 1024; off <<= 1) {
        int t = (tid >= off) ? sd[tid - off] : 0;
        __syncthreads();
        sd[tid] += t;
        __syncthreads();
    }
    if (tid < nb) boff[tid] = sd[tid] - v;
    if (tid == nb - 1) *rp_end = sd[tid];
}

__global__ void add_boff(int* __restrict__ rp, const int* __restrict__ boff, int n) {
    int i = blockIdx.x * 256 + threadIdx.x;
    if (i < n) rp[i] += boff[blockIdx.x];
}

__global__ void scatter_edges(const int* __restrict__ src, const int* __restrict__ dst,
                              const float* __restrict__ ew, const int* __restrict__ rp,
                              int* __restrict__ tmp, int2* __restrict__ ep, int E) {
    int e = blockIdx.x * 256 + threadIdx.x;
    if (e < E) {
        int d = dst[e];
        int pos = rp[d] + atomicAdd(&tmp[d], 1);
        ep[pos] = make_int2(src[e], __float_as_int(ew[e]));
    }
}

// ---------------- tiny precomputes ----------------

// W [K, Nn] fp32 -> WT [Nn][K] bf16
__global__ __launch_bounds__(256) void cast_transpose(const float* __restrict__ W,
                                                      __bf16* __restrict__ WT,
                                                      int K, int Nn) {
    int i = blockIdx.x * 256 + threadIdx.x;
    if (i < K * Nn) {
        int k = i / Nn, n = i % Nn;
        WT[(size_t)n * K + k] = (__bf16)W[i];
    }
}

// W23T[n][k] = sum_j W2[k][j] * W3[j][n], k<256, n<64
__global__ __launch_bounds__(256) void make_w23t(const float* __restrict__ W2,
                                                 const float* __restrict__ W3,
                                                 __bf16* __restrict__ W23T) {
    int idx = blockIdx.x * 256 + threadIdx.x;
    int n = idx & 63, k = idx >> 6;
    float s = 0.f;
    for (int j = 0; j < 64; ++j) s = fmaf(W2[k * 64 + j], W3[j * 64 + n], s);
    W23T[n * 256 + k] = (__bf16)s;
}

// c[n] = sum_j b2[j] * W3[j][n]
__global__ void make_c(const float* __restrict__ b2, const float* __restrict__ W3,
                       float* __restrict__ c) {
    int n = threadIdx.x;
    float s = 0.f;
    for (int j = 0; j < 64; ++j) s = fmaf(b2[j], W3[j * 64 + n], s);
    c[n] = s;
}

// ------- MFMA GEMM 1: C[M,256] = bf16(A_f32[M,512]) @ W1[512,256] -----------
// fp32 A cast to bf16 during LDS staging (no separate cast pass). 128x128
// block tile, grid (M/128, 2); 4 waves in 2x2, wave = 64x64 = acc[4][4].

__global__ __launch_bounds__(256) void gemm1_fused(const float* __restrict__ A,
                                                   const __bf16* __restrict__ BT,
                                                   __bf16* __restrict__ C, int M) {
    const int K = 512;
    __shared__ __align__(16) __bf16 As[128 * 40];
    __shared__ __align__(16) __bf16 Bs[128 * 40];
    const int tid = threadIdx.x;
    const int wave = tid >> 6, lane = tid & 63;
    const int wm = wave >> 1, wn = wave & 1;
    const int quad = lane >> 4, l16 = lane & 15;
    const int bm = blockIdx.x * 128, bn = blockIdx.y * 128;
    f32x4 acc[4][4] = {};
    for (int k0 = 0; k0 < K; k0 += 32) {
#pragma unroll
        for (int it = 0; it < 4; ++it) {           // A: 128 rows x 32 k fp32
            int idx = tid + it * 256;              // 0..1023 float4s
            int row = idx >> 3, ch = idx & 7;
            int gm = bm + row;
            float4 v = (gm < M) ? *(const float4*)(A + (size_t)gm * K + k0 + ch * 4)
                                : make_float4(0.f, 0.f, 0.f, 0.f);
            bf16x4 o;
            o[0] = (__bf16)v.x; o[1] = (__bf16)v.y; o[2] = (__bf16)v.z; o[3] = (__bf16)v.w;
            *(bf16x4*)(As + row * 40 + ch * 4) = o;
        }
#pragma unroll
        for (int it = 0; it < 2; ++it) {           // B: 128 rows x 32 k bf16
            int idx = tid + it * 256;              // 0..511 bf16x8s
            int row = idx >> 2, ch = idx & 3;
            *(bf16x8*)(Bs + row * 40 + ch * 8) =
                *(const bf16x8*)(BT + (size_t)(bn + row) * K + k0 + ch * 8);
        }
        __syncthreads();
        bf16x8 a[4], b[4];
#pragma unroll
        for (int i = 0; i < 4; ++i)
            a[i] = *(bf16x8*)(As + (wm * 64 + i * 16 + l16) * 40 + quad * 8);
#pragma unroll
        for (int j = 0; j < 4; ++j)
            b[j] = *(bf16x8*)(Bs + (wn * 64 + j * 16 + l16) * 40 + quad * 8);
#pragma unroll
        for (int i = 0; i < 4; ++i)
#pragma unroll
            for (int j = 0; j < 4; ++j)
                acc[i][j] = __builtin_amdgcn_mfma_f32_16x16x32_bf16(a[i], b[j], acc[i][j], 0, 0, 0);
        __syncthreads();
    }
#pragma unroll
    for (int i = 0; i < 4; ++i)
#pragma unroll
        for (int j = 0; j < 4; ++j)
#pragma unroll
            for (int rr = 0; rr < 4; ++rr) {
                int row = bm + wm * 64 + i * 16 + quad * 4 + rr;
                int col = bn + wn * 64 + j * 16 + l16;
                if (row < M) C[(size_t)row * 256 + col] = (__bf16)acc[i][j][rr];
            }
}

// ---------------- MFMA GEMM 2: C[M,64] = A[M,256] @ B[256,64] ---------------

__global__ __launch_bounds__(256) void gemm2_mfma(const __bf16* __restrict__ A,
                                                  const __bf16* __restrict__ BT,
                                                  __bf16* __restrict__ C, int M) {
    const int K = 256, Nn = 64;
    __shared__ __align__(16) __bf16 Bs[64 * 264];
    __shared__ __align__(16) __bf16 As[128 * 40];
    const int tid = threadIdx.x;
    const int wave = tid >> 6, lane = tid & 63;
    const int quad = lane >> 4, l16 = lane & 15;
    const int bm = blockIdx.x * 128;
#pragma unroll
    for (int it = 0; it < 8; ++it) {
        int e = tid + it * 256;
        int row = e >> 5, ch = e & 31;
        *(bf16x8*)(Bs + row * 264 + ch * 8) = *(const bf16x8*)(BT + row * 256 + ch * 8);
    }
    f32x4 acc[2][4] = {};
    for (int k0 = 0; k0 < K; k0 += 32) {
#pragma unroll
        for (int it = 0; it < 2; ++it) {
            int e = tid + it * 256;
            int row = e >> 2, ch = e & 3;
            int gm = bm + row;
            bf16x8 v = {};
            if (gm < M) v = *(const bf16x8*)(A + (size_t)gm * K + k0 + ch * 8);
            *(bf16x8*)(As + row * 40 + ch * 8) = v;
        }
        __syncthreads();
        bf16x8 a[2], b[4];
#pragma unroll
        for (int i = 0; i < 2; ++i)
            a[i] = *(bf16x8*)(As + (wave * 32 + i * 16 + l16) * 40 + quad * 8);
#pragma unroll
        for (int j = 0; j < 4; ++j)
            b[j] = *(bf16x8*)(Bs + (j * 16 + l16) * 264 + k0 + quad * 8);
#pragma unroll
        for (int i = 0; i < 2; ++i)
#pragma unroll
            for (int j = 0; j < 4; ++j)
                acc[i][j] = __builtin_amdgcn_mfma_f32_16x16x32_bf16(a[i], b[j], acc[i][j], 0, 0, 0);
        __syncthreads();
    }
#pragma unroll
    for (int i = 0; i < 2; ++i)
#pragma unroll
        for (int j = 0; j < 4; ++j)
#pragma unroll
            for (int rr = 0; rr < 4; ++rr) {
                int row = bm + wave * 32 + i * 16 + quad * 4 + rr;
                int col = j * 16 + l16;
                if (row < M) C[(size_t)row * Nn + col] = (__bf16)acc[i][j][rr];
            }
}

// ---------------- pull-mode SpMM ----------------

// 256-feat: wave per node; half=lane>>5 picks edge slot, c=lane&31 picks 16B
// chunk of the 512B row. 8 edges per iteration -> 4x16B gathers in flight.
__global__ __launch_bounds__(256) void spmm256_bf16(const __bf16* __restrict__ h,
                                                    const int* __restrict__ rp,
                                                    const int2* __restrict__ ep,
                                                    const float* __restrict__ bias,
                                                    __bf16* __restrict__ out, int n) {
    int node = blockIdx.x * 4 + (threadIdx.x >> 6);
    if (node >= n) return;
    int lane = threadIdx.x & 63;
    int half = lane >> 5, c = lane & 31;
    int e0 = rp[node], e1 = rp[node + 1];
    float acc[8] = {};
    for (int e = e0; e < e1; e += 8) {
#pragma unroll
        for (int u = 0; u < 4; ++u) {
            int ee = e + u * 2 + half;
            int cl = min(ee, e1 - 1);
            int2 p = ep[cl];
            float w = (ee < e1) ? __int_as_float(p.y) : 0.f;
            bf16x8 v = *(const bf16x8*)(h + (size_t)p.x * 256 + c * 8);
#pragma unroll
            for (int i = 0; i < 8; ++i) acc[i] = fmaf(w, (float)v[i], acc[i]);
        }
    }
#pragma unroll
    for (int i = 0; i < 8; ++i) acc[i] += __shfl_xor(acc[i], 32);
    if (half == 0) {
        float4 b0 = *(const float4*)(bias + c * 8);
        float4 b1 = *(const float4*)(bias + c * 8 + 4);
        bf16x8 o;
        o[0] = (__bf16)fmaxf(acc[0] + b0.x, 0.f);
        o[1] = (__bf16)fmaxf(acc[1] + b0.y, 0.f);
        o[2] = (__bf16)fmaxf(acc[2] + b0.z, 0.f);
        o[3] = (__bf16)fmaxf(acc[3] + b0.w, 0.f);
        o[4] = (__bf16)fmaxf(acc[4] + b1.x, 0.f);
        o[5] = (__bf16)fmaxf(acc[5] + b1.y, 0.f);
        o[6] = (__bf16)fmaxf(acc[6] + b1.z, 0.f);
        o[7] = (__bf16)fmaxf(acc[7] + b1.w, 0.f);
        *(bf16x8*)(out + (size_t)node * 256 + c * 8) = o;
    }
}

// 64-feat pass 1: t1 = spmm(g3) bf16, degw = rowsum(w).
// g=lane>>3 picks one of 8 parallel edges, c=lane&7 picks 16B chunk (8 feats).
__global__ __launch_bounds__(256) void spmm64_a(const __bf16* __restrict__ h,
                                                const int* __restrict__ rp,
                                                const int2* __restrict__ ep,
                                                __bf16* __restrict__ out,
                                                float* __restrict__ degw, int n) {
    int node = blockIdx.x * 4 + (threadIdx.x >> 6);
    if (node >= n) return;
    int lane = threadIdx.x & 63;
    int g = lane >> 3, c = lane & 7;
    int e0 = rp[node], e1 = rp[node + 1];
    float acc[8] = {};
    float ws = 0.f;
    for (int e = e0; e < e1; e += 16) {
#pragma unroll
        for (int u = 0; u < 2; ++u) {
            int ee = e + u * 8 + g;
            int cl = min(ee, e1 - 1);
            int2 p = ep[cl];
            float w = (ee < e1) ? __int_as_float(p.y) : 0.f;
            bf16x8 v = *(const bf16x8*)(h + (size_t)p.x * 64 + c * 8);
#pragma unroll
            for (int i = 0; i < 8; ++i) acc[i] = fmaf(w, (float)v[i], acc[i]);
            ws += w;
        }
    }
#pragma unroll
    for (int off = 8; off <= 32; off <<= 1) {
        ws += __shfl_xor(ws, off);
#pragma unroll
        for (int i = 0; i < 8; ++i) acc[i] += __shfl_xor(acc[i], off);
    }
    if (lane == 0) degw[node] = ws;
    if (g == 0) {
        bf16x8 o;
#pragma unroll
        for (int i = 0; i < 8; ++i) o[i] = (__bf16)acc[i];
        *(bf16x8*)(out + (size_t)node * 64 + c * 8) = o;
    }
}

// 64-feat pass 2: out = log_softmax(spmm(t1) + degw*cvec + r), fp32.
__global__ __launch_bounds__(256) void spmm64_b(const __bf16* __restrict__ h,
                                                const int* __restrict__ rp,
                                                const int2* __restrict__ ep,
                                                const float* __restrict__ degw,
                                                const float* __restrict__ cvec,
                                                const float* __restrict__ r,
                                                float* __restrict__ out, int n) {
    int node = blockIdx.x * 4 + (threadIdx.x >> 6);
    if (node >= n) return;
    int lane = threadIdx.x & 63;
    int g = lane >> 3, c = lane & 7;
    int e0 = rp[node], e1 = rp[node + 1];
    float acc[8] = {};
    for (int e = e0; e < e1; e += 16) {
#pragma unroll
        for (int u = 0; u < 2; ++u) {
            int ee = e + u * 8 + g;
            int cl = min(ee, e1 - 1);
            int2 p = ep[cl];
            float w = (ee < e1) ? __int_as_float(p.y) : 0.f;
            bf16x8 v = *(const bf16x8*)(h + (size_t)p.x * 64 + c * 8);
#pragma unroll
            for (int i = 0; i < 8; ++i) acc[i] = fmaf(w, (float)v[i], acc[i]);
        }
    }
#pragma unroll
    for (int off = 8; off <= 32; off <<= 1)
#pragma unroll
        for (int i = 0; i < 8; ++i) acc[i] += __shfl_xor(acc[i], off);
    float dw = degw[node];
    float4 c0 = *(const float4*)(cvec + c * 8), c1 = *(const float4*)(cvec + c * 8 + 4);
    float4 r0 = *(const float4*)(r + c * 8),    r1 = *(const float4*)(r + c * 8 + 4);
    float v[8];
    v[0] = acc[0] + dw * c0.x + r0.x; v[1] = acc[1] + dw * c0.y + r0.y;
    v[2] = acc[2] + dw * c0.z + r0.z; v[3] = acc[3] + dw * c0.w + r0.w;
    v[4] = acc[4] + dw * c1.x + r1.x; v[5] = acc[5] + dw * c1.y + r1.y;
    v[6] = acc[6] + dw * c1.z + r1.z; v[7] = acc[7] + dw * c1.w + r1.w;
    float m = v[0];
#pragma unroll
    for (int i = 1; i < 8; ++i) m = fmaxf(m, v[i]);
#pragma unroll
    for (int off = 1; off <= 4; off <<= 1) m = fmaxf(m, __shfl_xor(m, off));
    float s = 0.f;
#pragma unroll
    for (int i = 0; i < 8; ++i) s += __expf(v[i] - m);
#pragma unroll
    for (int off = 1; off <= 4; off <<= 1) s += __shfl_xor(s, off);
    float ls = m + __logf(s);
    if (g == 0) {
        float4 o0 = make_float4(v[0] - ls, v[1] - ls, v[2] - ls, v[3] - ls);
        float4 o1 = make_float4(v[4] - ls, v[5] - ls, v[6] - ls, v[7] - ls);
        *(float4*)(out + (size_t)node * 64 + c * 8) = o0;
        *(float4*)(out + (size_t)node * 64 + c * 8 + 4) = o1;
    }
}

// ---------------------------------------------------------------------------

extern "C" void kernel_launch(void* const* d_in, const int* in_sizes, int n_in,
                              void* d_out, int out_size, void* d_ws, size_t ws_size,
                              hipStream_t stream) {
    const float* x   = (const float*)d_in[0];
    const int*   src = (const int*)d_in[1];
    const int*   dst = (const int*)d_in[2];
    const float* ew  = (const float*)d_in[3];
    const float* W1  = (const float*)d_in[4];
    const float* b1  = (const float*)d_in[5];
    const float* W2  = (const float*)d_in[6];
    const float* b2  = (const float*)d_in[7];
    const float* W3  = (const float*)d_in[8];
    const float* r   = (const float*)d_in[9];

    const int N = in_sizes[0] / 512;   // 100000
    const int E = in_sizes[1];         // 3200000
    const int nb = (N + 255) / 256;

    // ---- workspace layout ----
    char* ws = (char*)d_ws;
    __bf16* h1 = (__bf16*)ws;                            // N*256 bf16 @ 0
    char* regB = ws + (size_t)N * 512;
    __bf16* h0b  = (__bf16*)regB;                        // N*256 bf16
    __bf16* g3   = (__bf16*)regB;                        // reuse after spmm256
    __bf16* t1   = (__bf16*)(regB + (size_t)N * 128);
    float*  degw = (float*)(regB + (size_t)N * 256);
    char* regC = regB + (size_t)N * 512;
    __bf16* W1T  = (__bf16*)regC;                        // 512*256 bf16
    __bf16* W23T = (__bf16*)(regC + 512 * 256 * 2);      // 64*256 bf16
    float*  cvec = (float*)(regC + 512 * 256 * 2 + 64 * 256 * 2);
    int* bsum = (int*)(regC + 512 * 256 * 2 + 64 * 256 * 2 + 256);
    int* boff = bsum + 1024;
    char* regD = regC + 512 * 1024;
    int*  rp  = (int*)regD;                              // N+1
    int*  tmp = rp + (N + 1);                            // N
    int2* ep  = (int2*)(tmp + N);                        // E pairs

    // ---- CSR build ----
    hipMemsetAsync(tmp, 0, (size_t)N * sizeof(int), stream);
    count_edges<<<(E + 255) / 256, 256, 0, stream>>>(dst, tmp, E);
    scan_block<<<nb, 256, 0, stream>>>(tmp, rp, bsum, N);
    scan_bsum<<<1, 1024, 0, stream>>>(bsum, boff, nb, rp + N);
    add_boff<<<nb, 256, 0, stream>>>(rp, boff, N);
    hipMemsetAsync(tmp, 0, (size_t)N * sizeof(int), stream);
    scatter_edges<<<(E + 255) / 256, 256, 0, stream>>>(src, dst, ew, rp, tmp, ep, E);

    // ---- precomputes ----
    cast_transpose<<<(512 * 256 + 255) / 256, 256, 0, stream>>>(W1, W1T, 512, 256);
    make_w23t<<<64, 256, 0, stream>>>(W2, W3, W23T);
    make_c<<<1, 64, 0, stream>>>(b2, W3, cvec);

    // ---- layer 1 ----
    dim3 g1((N + 127) / 128, 2);
    gemm1_fused<<<g1, 256, 0, stream>>>(x, W1T, h0b, N);
    spmm256_bf16<<<(N + 3) / 4, 256, 0, stream>>>(h0b, rp, ep, b1, h1, N);

    // ---- fused layers 2+3 ----
    gemm2_mfma<<<(N + 127) / 128, 256, 0, stream>>>(h1, W23T, g3, N);
    spmm64_a<<<(N + 3) / 4, 256, 0, stream>>>(g3, rp, ep, t1, degw, N);
    spmm64_b<<<(N + 3) / 4, 256, 0, stream>>>(t1, rp, ep, degw, cvec, r, (float*)d_out, N);
}

// Round 6
// 925.220 us; speedup vs baseline: 2.3923x; 1.1488x over previous
//
#include <hip/hip_runtime.h>
#include <math.h>

// ---------------------------------------------------------------------------
// StatusGCN restructured:
//   h0 = fp8e4m3(x @ W1)              (MFMA, fp32 A cast in staging) [N,256]
//   h1 = bf16(relu(spmm(h0) + b1))                                  [N,256]
//   g3 = bf16(h1 @ (W2@W3))           (MFMA)                        [N,64]
//   t1 = bf16(spmm(g3)); degw = rowsum(w)                           [N,64]
//   out = log_softmax(spmm(t1) + degw*(b2@W3) + r)                  [N,64] f32
// Identities: spmm(X)@W == spmm(X@W);  spmm(X + 1*c) == spmm(X) + degw*c.
// h0 is fp8 ONLY to halve the dominant spmm256 gather (1.64 GB -> 0.82 GB);
// the 64-wide tail tensors stay bf16 (closer to output, tighter error budget).
// NOTE (r4 post-mortem): keep per-wave MFMA tile at 64x64 (acc[4][4]=64 AGPR).
// acc[4][8] put wave reg total >256 on the unified VGPR/AGPR file -> 1
// wave/SIMD -> 9.5% occupancy. Widen the BLOCK (more waves), never the wave.
// ---------------------------------------------------------------------------

typedef __bf16 bf16x8 __attribute__((ext_vector_type(8)));
typedef __bf16 bf16x4 __attribute__((ext_vector_type(4)));
typedef float f32x4 __attribute__((ext_vector_type(4)));
typedef float f32x2 __attribute__((ext_vector_type(2)));

// ---------------- CSR construction ----------------

__global__ void count_edges(const int* __restrict__ dst, int* __restrict__ cnt, int E) {
    int e = blockIdx.x * 256 + threadIdx.x;
    if (e < E) atomicAdd(&cnt[dst[e]], 1);
}

__global__ __launch_bounds__(256) void scan_block(const int* __restrict__ cnt,
                                                  int* __restrict__ rp,
                                                  int* __restrict__ bsum, int n) {
    __shared__ int sd[256];
    int i = blockIdx.x * 256 + threadIdx.x;
    int v = (i < n) ? cnt[i] : 0;
    sd[threadIdx.x] = v;
    __syncthreads();
    for (int off = 1; off < 256; off <<= 1) {
        int t = (threadIdx.x >= off) ? sd[threadIdx.x - off] : 0;
        __syncthreads();
        sd[threadIdx.x] += t;
        __syncthreads();
    }
    if (i < n) rp[i] = sd[threadIdx.x] - v;
    if (threadIdx.x == 255) bsum[blockIdx.x] = sd[255];
}

__global__ __launch_bounds__(1024) void scan_bsum(int* __restrict__ bsum,
                                                  int* __restrict__ boff,
                                                  int nb, int* __restrict__ rp_end) {
    __shared__ int sd[1024];
    int tid = threadIdx.x;
    int v = (tid < nb) ? bsum[tid] : 0;
    sd[tid] = v;
    __syncthreads();
    for (int off = 1; off < 1024; off <<= 1) {
        int t = (tid >= off) ? sd[tid - off] : 0;
        __syncthreads();
        sd[tid] += t;
        __syncthreads();
    }
    if (tid < nb) boff[tid] = sd[tid] - v;
    if (tid == nb - 1) *rp_end = sd[tid];
}

__global__ void add_boff(int* __restrict__ rp, const int* __restrict__ boff, int n) {
    int i = blockIdx.x * 256 + threadIdx.x;
    if (i < n) rp[i] += boff[blockIdx.x];
}

__global__ void scatter_edges(const int* __restrict__ src, const int* __restrict__ dst,
                              const float* __restrict__ ew, const int* __restrict__ rp,
                              int* __restrict__ tmp, int2* __restrict__ ep, int E) {
    int e = blockIdx.x * 256 + threadIdx.x;
    if (e < E) {
        int d = dst[e];
        int pos = rp[d] + atomicAdd(&tmp[d], 1);
        ep[pos] = make_int2(src[e], __float_as_int(ew[e]));
    }
}

// ---------------- tiny precomputes ----------------

// W [K, Nn] fp32 -> WT [Nn][K] bf16
__global__ __launch_bounds__(256) void cast_transpose(const float* __restrict__ W,
                                                      __bf16* __restrict__ WT,
                                                      int K, int Nn) {
    int i = blockIdx.x * 256 + threadIdx.x;
    if (i < K * Nn) {
        int k = i / Nn, n = i % Nn;
        WT[(size_t)n * K + k] = (__bf16)W[i];
    }
}

// W23T[n][k] = sum_j W2[k][j] * W3[j][n], k<256, n<64
__global__ __launch_bounds__(256) void make_w23t(const float* __restrict__ W2,
                                                 const float* __restrict__ W3,
                                                 __bf16* __restrict__ W23T) {
    int idx = blockIdx.x * 256 + threadIdx.x;
    int n = idx & 63, k = idx >> 6;
    float s = 0.f;
    for (int j = 0; j < 64; ++j) s = fmaf(W2[k * 64 + j], W3[j * 64 + n], s);
    W23T[n * 256 + k] = (__bf16)s;
}

// c[n] = sum_j b2[j] * W3[j][n]
__global__ void make_c(const float* __restrict__ b2, const float* __restrict__ W3,
                       float* __restrict__ c) {
    int n = threadIdx.x;
    float s = 0.f;
    for (int j = 0; j < 64; ++j) s = fmaf(b2[j], W3[j * 64 + n], s);
    c[n] = s;
}

// ------- MFMA GEMM 1: h0_fp8[M,256] = bf16(A_f32[M,512]) @ W1[512,256] ------
// 512 threads = 8 waves in 2x4; block tile 128x256 (full N) so x is read
// exactly once. Per-wave 64x64 = acc[4][4] (see r4 note).

__global__ __launch_bounds__(512) void gemm1_fused(const float* __restrict__ A,
                                                   const __bf16* __restrict__ BT,
                                                   unsigned char* __restrict__ C, int M) {
    const int K = 512;
    __shared__ __align__(16) __bf16 As[128 * 40];
    __shared__ __align__(16) __bf16 Bs[256 * 40];
    const int tid = threadIdx.x;
    const int wave = tid >> 6, lane = tid & 63;
    const int wm = wave >> 2, wn = wave & 3;
    const int quad = lane >> 4, l16 = lane & 15;
    const int bm = blockIdx.x * 128;
    f32x4 acc[4][4] = {};
    for (int k0 = 0; k0 < K; k0 += 32) {
#pragma unroll
        for (int it = 0; it < 2; ++it) {           // A: 128 rows x 32 k fp32
            int idx = tid + it * 512;              // 0..1023 float4s
            int row = idx >> 3, ch = idx & 7;
            int gm = bm + row;
            float4 v = (gm < M) ? *(const float4*)(A + (size_t)gm * K + k0 + ch * 4)
                                : make_float4(0.f, 0.f, 0.f, 0.f);
            bf16x4 o;
            o[0] = (__bf16)v.x; o[1] = (__bf16)v.y; o[2] = (__bf16)v.z; o[3] = (__bf16)v.w;
            *(bf16x4*)(As + row * 40 + ch * 4) = o;
        }
#pragma unroll
        for (int it = 0; it < 2; ++it) {           // B: 256 rows x 32 k bf16
            int idx = tid + it * 512;              // 0..1023 bf16x8s
            int row = idx >> 2, ch = idx & 3;
            *(bf16x8*)(Bs + row * 40 + ch * 8) =
                *(const bf16x8*)(BT + (size_t)row * K + k0 + ch * 8);
        }
        __syncthreads();
        bf16x8 a[4], b[4];
#pragma unroll
        for (int i = 0; i < 4; ++i)
            a[i] = *(bf16x8*)(As + (wm * 64 + i * 16 + l16) * 40 + quad * 8);
#pragma unroll
        for (int j = 0; j < 4; ++j)
            b[j] = *(bf16x8*)(Bs + (wn * 64 + j * 16 + l16) * 40 + quad * 8);
#pragma unroll
        for (int i = 0; i < 4; ++i)
#pragma unroll
            for (int j = 0; j < 4; ++j)
                acc[i][j] = __builtin_amdgcn_mfma_f32_16x16x32_bf16(a[i], b[j], acc[i][j], 0, 0, 0);
        __syncthreads();
    }
#pragma unroll
    for (int i = 0; i < 4; ++i)
#pragma unroll
        for (int j = 0; j < 4; ++j)
#pragma unroll
            for (int rr = 0; rr < 4; ++rr) {
                int row = bm + wm * 64 + i * 16 + quad * 4 + rr;
                int col = wn * 64 + j * 16 + l16;
                if (row < M) {
                    unsigned int p = __builtin_amdgcn_cvt_pk_fp8_f32(acc[i][j][rr],
                                                                     acc[i][j][rr], 0, false);
                    C[(size_t)row * 256 + col] = (unsigned char)(p & 0xff);
                }
            }
}

// ---------------- MFMA GEMM 2: C[M,64] = A[M,256] @ B[256,64] ---------------

__global__ __launch_bounds__(256) void gemm2_mfma(const __bf16* __restrict__ A,
                                                  const __bf16* __restrict__ BT,
                                                  __bf16* __restrict__ C, int M) {
    const int K = 256, Nn = 64;
    __shared__ __align__(16) __bf16 Bs[64 * 264];
    __shared__ __align__(16) __bf16 As[128 * 40];
    const int tid = threadIdx.x;
    const int wave = tid >> 6, lane = tid & 63;
    const int quad = lane >> 4, l16 = lane & 15;
    const int bm = blockIdx.x * 128;
#pragma unroll
    for (int it = 0; it < 8; ++it) {
        int e = tid + it * 256;
        int row = e >> 5, ch = e & 31;
        *(bf16x8*)(Bs + row * 264 + ch * 8) = *(const bf16x8*)(BT + row * 256 + ch * 8);
    }
    f32x4 acc[2][4] = {};
    for (int k0 = 0; k0 < K; k0 += 32) {
#pragma unroll
        for (int it = 0; it < 2; ++it) {
            int e = tid + it * 256;
            int row = e >> 2, ch = e & 3;
            int gm = bm + row;
            bf16x8 v = {};
            if (gm < M) v = *(const bf16x8*)(A + (size_t)gm * K + k0 + ch * 8);
            *(bf16x8*)(As + row * 40 + ch * 8) = v;
        }
        __syncthreads();
        bf16x8 a[2], b[4];
#pragma unroll
        for (int i = 0; i < 2; ++i)
            a[i] = *(bf16x8*)(As + (wave * 32 + i * 16 + l16) * 40 + quad * 8);
#pragma unroll
        for (int j = 0; j < 4; ++j)
            b[j] = *(bf16x8*)(Bs + (j * 16 + l16) * 264 + k0 + quad * 8);
#pragma unroll
        for (int i = 0; i < 2; ++i)
#pragma unroll
            for (int j = 0; j < 4; ++j)
                acc[i][j] = __builtin_amdgcn_mfma_f32_16x16x32_bf16(a[i], b[j], acc[i][j], 0, 0, 0);
        __syncthreads();
    }
#pragma unroll
    for (int i = 0; i < 2; ++i)
#pragma unroll
        for (int j = 0; j < 4; ++j)
#pragma unroll
            for (int rr = 0; rr < 4; ++rr) {
                int row = bm + wave * 32 + i * 16 + quad * 4 + rr;
                int col = j * 16 + l16;
                if (row < M) C[(size_t)row * Nn + col] = (__bf16)acc[i][j][rr];
            }
}

// ---------------- pull-mode SpMM ----------------

// 256-feat, fp8 gather: wave per node; half=lane>>5 picks edge slot, c=lane&31
// picks the 8B chunk (8 fp8 feats) of the 256B row. 8 edges per iteration.
__global__ __launch_bounds__(256) void spmm256_fp8(const unsigned char* __restrict__ h,
                                                   const int* __restrict__ rp,
                                                   const int2* __restrict__ ep,
                                                   const float* __restrict__ bias,
                                                   __bf16* __restrict__ out, int n) {
    int node = blockIdx.x * 4 + (threadIdx.x >> 6);
    if (node >= n) return;
    int lane = threadIdx.x & 63;
    int half = lane >> 5, c = lane & 31;
    int e0 = rp[node], e1 = rp[node + 1];
    float acc[8] = {};
    for (int e = e0; e < e1; e += 8) {
#pragma unroll
        for (int u = 0; u < 4; ++u) {
            int ee = e + u * 2 + half;
            int cl = min(ee, e1 - 1);
            int2 p = ep[cl];
            float w = (ee < e1) ? __int_as_float(p.y) : 0.f;
            uint2 v = *(const uint2*)(h + (size_t)p.x * 256 + c * 8);
            f32x2 f0 = __builtin_amdgcn_cvt_pk_f32_fp8(v.x, false);
            f32x2 f1 = __builtin_amdgcn_cvt_pk_f32_fp8(v.x, true);
            f32x2 f2 = __builtin_amdgcn_cvt_pk_f32_fp8(v.y, false);
            f32x2 f3 = __builtin_amdgcn_cvt_pk_f32_fp8(v.y, true);
            acc[0] = fmaf(w, f0.x, acc[0]); acc[1] = fmaf(w, f0.y, acc[1]);
            acc[2] = fmaf(w, f1.x, acc[2]); acc[3] = fmaf(w, f1.y, acc[3]);
            acc[4] = fmaf(w, f2.x, acc[4]); acc[5] = fmaf(w, f2.y, acc[5]);
            acc[6] = fmaf(w, f3.x, acc[6]); acc[7] = fmaf(w, f3.y, acc[7]);
        }
    }
#pragma unroll
    for (int i = 0; i < 8; ++i) acc[i] += __shfl_xor(acc[i], 32);
    if (half == 0) {
        float4 b0 = *(const float4*)(bias + c * 8);
        float4 b1 = *(const float4*)(bias + c * 8 + 4);
        bf16x8 o;
        o[0] = (__bf16)fmaxf(acc[0] + b0.x, 0.f);
        o[1] = (__bf16)fmaxf(acc[1] + b0.y, 0.f);
        o[2] = (__bf16)fmaxf(acc[2] + b0.z, 0.f);
        o[3] = (__bf16)fmaxf(acc[3] + b0.w, 0.f);
        o[4] = (__bf16)fmaxf(acc[4] + b1.x, 0.f);
        o[5] = (__bf16)fmaxf(acc[5] + b1.y, 0.f);
        o[6] = (__bf16)fmaxf(acc[6] + b1.z, 0.f);
        o[7] = (__bf16)fmaxf(acc[7] + b1.w, 0.f);
        *(bf16x8*)(out + (size_t)node * 256 + c * 8) = o;
    }
}

// 64-feat pass 1: t1 = spmm(g3) bf16, degw = rowsum(w).
__global__ __launch_bounds__(256) void spmm64_a(const __bf16* __restrict__ h,
                                                const int* __restrict__ rp,
                                                const int2* __restrict__ ep,
                                                __bf16* __restrict__ out,
                                                float* __restrict__ degw, int n) {
    int node = blockIdx.x * 4 + (threadIdx.x >> 6);
    if (node >= n) return;
    int lane = threadIdx.x & 63;
    int g = lane >> 3, c = lane & 7;
    int e0 = rp[node], e1 = rp[node + 1];
    float acc[8] = {};
    float ws = 0.f;
    for (int e = e0; e < e1; e += 16) {
#pragma unroll
        for (int u = 0; u < 2; ++u) {
            int ee = e + u * 8 + g;
            int cl = min(ee, e1 - 1);
            int2 p = ep[cl];
            float w = (ee < e1) ? __int_as_float(p.y) : 0.f;
            bf16x8 v = *(const bf16x8*)(h + (size_t)p.x * 64 + c * 8);
#pragma unroll
            for (int i = 0; i < 8; ++i) acc[i] = fmaf(w, (float)v[i], acc[i]);
            ws += w;
        }
    }
#pragma unroll
    for (int off = 8; off <= 32; off <<= 1) {
        ws += __shfl_xor(ws, off);
#pragma unroll
        for (int i = 0; i < 8; ++i) acc[i] += __shfl_xor(acc[i], off);
    }
    if (lane == 0) degw[node] = ws;
    if (g == 0) {
        bf16x8 o;
#pragma unroll
        for (int i = 0; i < 8; ++i) o[i] = (__bf16)acc[i];
        *(bf16x8*)(out + (size_t)node * 64 + c * 8) = o;
    }
}

// 64-feat pass 2: out = log_softmax(spmm(t1) + degw*cvec + r), fp32.
__global__ __launch_bounds__(256) void spmm64_b(const __bf16* __restrict__ h,
                                                const int* __restrict__ rp,
                                                const int2* __restrict__ ep,
                                                const float* __restrict__ degw,
                                                const float* __restrict__ cvec,
                                                const float* __restrict__ r,
                                                float* __restrict__ out, int n) {
    int node = blockIdx.x * 4 + (threadIdx.x >> 6);
    if (node >= n) return;
    int lane = threadIdx.x & 63;
    int g = lane >> 3, c = lane & 7;
    int e0 = rp[node], e1 = rp[node + 1];
    float acc[8] = {};
    for (int e = e0; e < e1; e += 16) {
#pragma unroll
        for (int u = 0; u < 2; ++u) {
            int ee = e + u * 8 + g;
            int cl = min(ee, e1 - 1);
            int2 p = ep[cl];
            float w = (ee < e1) ? __int_as_float(p.y) : 0.f;
            bf16x8 v = *(const bf16x8*)(h + (size_t)p.x * 64 + c * 8);
#pragma unroll
            for (int i = 0; i < 8; ++i) acc[i] = fmaf(w, (float)v[i], acc[i]);
        }
    }
#pragma unroll
    for (int off = 8; off <= 32; off <<= 1)
#pragma unroll
        for (int i = 0; i < 8; ++i) acc[i] += __shfl_xor(acc[i], off);
    float dw = degw[node];
    float4 c0 = *(const float4*)(cvec + c * 8), c1 = *(const float4*)(cvec + c * 8 + 4);
    float4 r0 = *(const float4*)(r + c * 8),    r1 = *(const float4*)(r + c * 8 + 4);
    float v[8];
    v[0] = acc[0] + dw * c0.x + r0.x; v[1] = acc[1] + dw * c0.y + r0.y;
    v[2] = acc[2] + dw * c0.z + r0.z; v[3] = acc[3] + dw * c0.w + r0.w;
    v[4] = acc[4] + dw * c1.x + r1.x; v[5] = acc[5] + dw * c1.y + r1.y;
    v[6] = acc[6] + dw * c1.z + r1.z; v[7] = acc[7] + dw * c1.w + r1.w;
    float m = v[0];
#pragma unroll
    for (int i = 1; i < 8; ++i) m = fmaxf(m, v[i]);
#pragma unroll
    for (int off = 1; off <= 4; off <<= 1) m = fmaxf(m, __shfl_xor(m, off));
    float s = 0.f;
#pragma unroll
    for (int i = 0; i < 8; ++i) s += __expf(v[i] - m);
#pragma unroll
    for (int off = 1; off <= 4; off <<= 1) s += __shfl_xor(s, off);
    float ls = m + __logf(s);
    if (g == 0) {
        float4 o0 = make_float4(v[0] - ls, v[1] - ls, v[2] - ls, v[3] - ls);
        float4 o1 = make_float4(v[4] - ls, v[5] - ls, v[6] - ls, v[7] - ls);
        *(float4*)(out + (size_t)node * 64 + c * 8) = o0;
        *(float4*)(out + (size_t)node * 64 + c * 8 + 4) = o1;
    }
}

// ---------------------------------------------------------------------------

extern "C" void kernel_launch(void* const* d_in, const int* in_sizes, int n_in,
                              void* d_out, int out_size, void* d_ws, size_t ws_size,
                              hipStream_t stream) {
    const float* x   = (const float*)d_in[0];
    const int*   src = (const int*)d_in[1];
    const int*   dst = (const int*)d_in[2];
    const float* ew  = (const float*)d_in[3];
    const float* W1  = (const float*)d_in[4];
    const float* b1  = (const float*)d_in[5];
    const float* W2  = (const float*)d_in[6];
    const float* b2  = (const float*)d_in[7];
    const float* W3  = (const float*)d_in[8];
    const float* r   = (const float*)d_in[9];

    const int N = in_sizes[0] / 512;   // 100000
    const int E = in_sizes[1];         // 3200000
    const int nb = (N + 255) / 256;

    // ---- workspace layout ----
    char* ws = (char*)d_ws;
    __bf16* h1 = (__bf16*)ws;                            // N*256 bf16 @ 0
    char* regB = ws + (size_t)N * 512;
    unsigned char* h0f = (unsigned char*)regB;           // N*256 fp8
    __bf16* g3   = (__bf16*)regB;                        // reuse after spmm256
    __bf16* t1   = (__bf16*)(regB + (size_t)N * 128);
    float*  degw = (float*)(regB + (size_t)N * 256);
    char* regC = regB + (size_t)N * 512;
    __bf16* W1T  = (__bf16*)regC;                        // 512*256 bf16
    __bf16* W23T = (__bf16*)(regC + 512 * 256 * 2);      // 64*256 bf16
    float*  cvec = (float*)(regC + 512 * 256 * 2 + 64 * 256 * 2);
    int* bsum = (int*)(regC + 512 * 256 * 2 + 64 * 256 * 2 + 256);
    int* boff = bsum + 1024;
    char* regD = regC + 512 * 1024;
    int*  rp  = (int*)regD;                              // N+1
    int*  tmp = rp + (N + 1);                            // N
    int2* ep  = (int2*)(tmp + N);                        // E pairs

    // ---- CSR build ----
    hipMemsetAsync(tmp, 0, (size_t)N * sizeof(int), stream);
    count_edges<<<(E + 255) / 256, 256, 0, stream>>>(dst, tmp, E);
    scan_block<<<nb, 256, 0, stream>>>(tmp, rp, bsum, N);
    scan_bsum<<<1, 1024, 0, stream>>>(bsum, boff, nb, rp + N);
    add_boff<<<nb, 256, 0, stream>>>(rp, boff, N);
    hipMemsetAsync(tmp, 0, (size_t)N * sizeof(int), stream);
    scatter_edges<<<(E + 255) / 256, 256, 0, stream>>>(src, dst, ew, rp, tmp, ep, E);

    // ---- precomputes ----
    cast_transpose<<<(512 * 256 + 255) / 256, 256, 0, stream>>>(W1, W1T, 512, 256);
    make_w23t<<<64, 256, 0, stream>>>(W2, W3, W23T);
    make_c<<<1, 64, 0, stream>>>(b2, W3, cvec);

    // ---- layer 1 ----
    gemm1_fused<<<(N + 127) / 128, 512, 0, stream>>>(x, W1T, h0f, N);
    spmm256_fp8<<<(N + 3) / 4, 256, 0, stream>>>(h0f, rp, ep, b1, h1, N);

    // ---- fused layers 2+3 ----
    gemm2_mfma<<<(N + 127) / 128, 256, 0, stream>>>(h1, W23T, g3, N);
    spmm64_a<<<(N + 3) / 4, 256, 0, stream>>>(g3, rp, ep, t1, degw, N);
    spmm64_b<<<(N + 3) / 4, 256, 0, stream>>>(t1, rp, ep, degw, cvec, r, (float*)d_out, N);
}

// Round 7
// 849.174 us; speedup vs baseline: 2.6065x; 1.0896x over previous
//
#include <hip/hip_runtime.h>
#include <math.h>

// ---------------------------------------------------------------------------
// StatusGCN restructured:
//   h0 = fp8e4m3(x @ W1)              (MFMA, fp32 A cast in staging) [N,256]
//   h1 = bf16(relu(spmm(h0) + b1))                                  [N,256]
//   g3 = bf16(h1 @ (W2@W3))           (MFMA)                        [N,64]
//   t1 = bf16(spmm(g3)); degw = rowsum(w)                           [N,64]
//   out = log_softmax(spmm(t1) + degw*(b2@W3) + r)                  [N,64] f32
// Identities: spmm(X)@W == spmm(X@W);  spmm(X + 1*c) == spmm(X) + degw*c.
// CSR build (r6 post-mortem): direct 8B random scatter had 8.7x write amp
// (222MB HBM writes for 25.6MB logical; 64B line-granule writebacks across
// 8 non-coherent XCD L2s). Replaced with 2-phase bucket sort:
//   pass1: LDS tile-sort by dst>>9 -> contiguous runs into bucket regions
//          (bursty writes, amp~1.2) + folded per-node counting.
//   pass2: one block per bucket, exact placement via LDS node cursors;
//          writes confined to one 131KB region per block -> amp~1.
// NOTE (r4 post-mortem): keep per-wave MFMA tile at 64x64 (acc[4][4]=64 AGPR).
// acc[4][8] put wave reg total >256 on the unified VGPR/AGPR file -> 1
// wave/SIMD -> 9.5% occupancy. Widen the BLOCK (more waves), never the wave.
// ---------------------------------------------------------------------------

typedef __bf16 bf16x8 __attribute__((ext_vector_type(8)));
typedef __bf16 bf16x4 __attribute__((ext_vector_type(4)));
typedef float f32x4 __attribute__((ext_vector_type(4)));
typedef float f32x2 __attribute__((ext_vector_type(2)));

// ---------------- CSR construction (bucketed 2-phase) ----------------

#define TILE 2048

// pass 1: tile-sorted scatter into per-bucket regions + per-node counting
__global__ __launch_bounds__(1024) void bucket_scatter(const int* __restrict__ src,
                                                       const int* __restrict__ dst,
                                                       const float* __restrict__ ew,
                                                       int* __restrict__ cnt,
                                                       int* __restrict__ gcnt,
                                                       int4* __restrict__ tb,
                                                       int E, int buckcap) {
    __shared__ int hist[256];
    __shared__ int hscan[256];
    __shared__ int gbase[256];
    __shared__ int4 stage[TILE];
    int tid = threadIdx.x;
    int e0 = blockIdx.x * TILE;
    int tilecnt = min(TILE, E - e0);
    if (tid < 256) hist[tid] = 0;
    __syncthreads();
    int myb[2], myr[2], ms[2], mw[2], md[2];
#pragma unroll
    for (int u = 0; u < 2; ++u) {
        int e = e0 + u * 1024 + tid;
        myb[u] = -1;
        if (e < E) {
            int d = dst[e];
            ms[u] = src[e];
            mw[u] = __float_as_int(ew[e]);
            md[u] = d;
            int b = d >> 9;
            myb[u] = b;
            myr[u] = atomicAdd(&hist[b], 1);   // rank within (tile, bucket)
            atomicAdd(&cnt[d], 1);             // per-node degree count
        }
    }
    __syncthreads();
    if (tid < 256) {
        hscan[tid] = hist[tid];
        gbase[tid] = (hist[tid] > 0) ? atomicAdd(&gcnt[tid], hist[tid]) : 0;
    }
    __syncthreads();
    for (int off = 1; off < 256; off <<= 1) {    // inclusive scan of hist
        int t = 0;
        if (tid < 256 && tid >= off) t = hscan[tid - off];
        __syncthreads();
        if (tid < 256) hscan[tid] += t;
        __syncthreads();
    }
#pragma unroll
    for (int u = 0; u < 2; ++u) {
        if (myb[u] >= 0) {
            int b = myb[u];
            stage[hscan[b] - hist[b] + myr[u]] = make_int4(ms[u], mw[u], md[u], 0);
        }
    }
    __syncthreads();
    for (int i = tid; i < tilecnt; i += 1024) {  // bursty, run-contiguous writes
        int4 ent = stage[i];
        int b = ent.z >> 9;
        int exc = hscan[b] - hist[b];
        tb[(size_t)b * buckcap + gbase[b] + (i - exc)] = ent;
    }
}

// pass 2: exact placement within each bucket via LDS node cursors
__global__ __launch_bounds__(1024) void bucket_place(const int4* __restrict__ tb,
                                                     const int* __restrict__ gcnt,
                                                     const int* __restrict__ rp,
                                                     int2* __restrict__ ep,
                                                     int N, int buckcap) {
    __shared__ int cursor[512];
    int b = blockIdx.x;
    int base = b << 9;
    int nn = min(512, N - base);
    int tid = threadIdx.x;
    if (tid < nn) cursor[tid] = rp[base + tid];
    __syncthreads();
    int cb = gcnt[b];
    for (int i = tid; i < cb; i += 1024) {
        int4 ent = tb[(size_t)b * buckcap + i];
        int pos = atomicAdd(&cursor[ent.z - base], 1);
        ep[pos] = make_int2(ent.x, ent.y);
    }
}

// two-level exclusive scan of cnt[n] -> rp
__global__ __launch_bounds__(256) void scan_block(const int* __restrict__ cnt,
                                                  int* __restrict__ rp,
                                                  int* __restrict__ bsum, int n) {
    __shared__ int sd[256];
    int i = blockIdx.x * 256 + threadIdx.x;
    int v = (i < n) ? cnt[i] : 0;
    sd[threadIdx.x] = v;
    __syncthreads();
    for (int off = 1; off < 256; off <<= 1) {
        int t = (threadIdx.x >= off) ? sd[threadIdx.x - off] : 0;
        __syncthreads();
        sd[threadIdx.x] += t;
        __syncthreads();
    }
    if (i < n) rp[i] = sd[threadIdx.x] - v;
    if (threadIdx.x == 255) bsum[blockIdx.x] = sd[255];
}

__global__ __launch_bounds__(1024) void scan_bsum(int* __restrict__ bsum,
                                                  int* __restrict__ boff,
                                                  int nb, int* __restrict__ rp_end) {
    __shared__ int sd[1024];
    int tid = threadIdx.x;
    int v = (tid < nb) ? bsum[tid] : 0;
    sd[tid] = v;
    __syncthreads();
    for (int off = 1; off < 1024; off <<= 1) {
        int t = (tid >= off) ? sd[tid - off] : 0;
        __syncthreads();
        sd[tid] += t;
        __syncthreads();
    }
    if (tid < nb) boff[tid] = sd[tid] - v;
    if (tid == nb - 1) *rp_end = sd[tid];
}

__global__ void add_boff(int* __restrict__ rp, const int* __restrict__ boff, int n) {
    int i = blockIdx.x * 256 + threadIdx.x;
    if (i < n) rp[i] += boff[blockIdx.x];
}

// ---------------- tiny precomputes ----------------

__global__ __launch_bounds__(256) void cast_transpose(const float* __restrict__ W,
                                                      __bf16* __restrict__ WT,
                                                      int K, int Nn) {
    int i = blockIdx.x * 256 + threadIdx.x;
    if (i < K * Nn) {
        int k = i / Nn, n = i % Nn;
        WT[(size_t)n * K + k] = (__bf16)W[i];
    }
}

__global__ __launch_bounds__(256) void make_w23t(const float* __restrict__ W2,
                                                 const float* __restrict__ W3,
                                                 __bf16* __restrict__ W23T) {
    int idx = blockIdx.x * 256 + threadIdx.x;
    int n = idx & 63, k = idx >> 6;
    float s = 0.f;
    for (int j = 0; j < 64; ++j) s = fmaf(W2[k * 64 + j], W3[j * 64 + n], s);
    W23T[n * 256 + k] = (__bf16)s;
}

__global__ void make_c(const float* __restrict__ b2, const float* __restrict__ W3,
                       float* __restrict__ c) {
    int n = threadIdx.x;
    float s = 0.f;
    for (int j = 0; j < 64; ++j) s = fmaf(b2[j], W3[j * 64 + n], s);
    c[n] = s;
}

// ------- MFMA GEMM 1: h0_fp8[M,256] = bf16(A_f32[M,512]) @ W1[512,256] ------

__global__ __launch_bounds__(512) void gemm1_fused(const float* __restrict__ A,
                                                   const __bf16* __restrict__ BT,
                                                   unsigned char* __restrict__ C, int M) {
    const int K = 512;
    __shared__ __align__(16) __bf16 As[128 * 40];
    __shared__ __align__(16) __bf16 Bs[256 * 40];
    const int tid = threadIdx.x;
    const int wave = tid >> 6, lane = tid & 63;
    const int wm = wave >> 2, wn = wave & 3;
    const int quad = lane >> 4, l16 = lane & 15;
    const int bm = blockIdx.x * 128;
    f32x4 acc[4][4] = {};
    for (int k0 = 0; k0 < K; k0 += 32) {
#pragma unroll
        for (int it = 0; it < 2; ++it) {
            int idx = tid + it * 512;
            int row = idx >> 3, ch = idx & 7;
            int gm = bm + row;
            float4 v = (gm < M) ? *(const float4*)(A + (size_t)gm * K + k0 + ch * 4)
                                : make_float4(0.f, 0.f, 0.f, 0.f);
            bf16x4 o;
            o[0] = (__bf16)v.x; o[1] = (__bf16)v.y; o[2] = (__bf16)v.z; o[3] = (__bf16)v.w;
            *(bf16x4*)(As + row * 40 + ch * 4) = o;
        }
#pragma unroll
        for (int it = 0; it < 2; ++it) {
            int idx = tid + it * 512;
            int row = idx >> 2, ch = idx & 3;
            *(bf16x8*)(Bs + row * 40 + ch * 8) =
                *(const bf16x8*)(BT + (size_t)row * K + k0 + ch * 8);
        }
        __syncthreads();
        bf16x8 a[4], b[4];
#pragma unroll
        for (int i = 0; i < 4; ++i)
            a[i] = *(bf16x8*)(As + (wm * 64 + i * 16 + l16) * 40 + quad * 8);
#pragma unroll
        for (int j = 0; j < 4; ++j)
            b[j] = *(bf16x8*)(Bs + (wn * 64 + j * 16 + l16) * 40 + quad * 8);
#pragma unroll
        for (int i = 0; i < 4; ++i)
#pragma unroll
            for (int j = 0; j < 4; ++j)
                acc[i][j] = __builtin_amdgcn_mfma_f32_16x16x32_bf16(a[i], b[j], acc[i][j], 0, 0, 0);
        __syncthreads();
    }
#pragma unroll
    for (int i = 0; i < 4; ++i)
#pragma unroll
        for (int j = 0; j < 4; ++j)
#pragma unroll
            for (int rr = 0; rr < 4; ++rr) {
                int row = bm + wm * 64 + i * 16 + quad * 4 + rr;
                int col = wn * 64 + j * 16 + l16;
                if (row < M) {
                    unsigned int p = __builtin_amdgcn_cvt_pk_fp8_f32(acc[i][j][rr],
                                                                     acc[i][j][rr], 0, false);
                    C[(size_t)row * 256 + col] = (unsigned char)(p & 0xff);
                }
            }
}

// ---------------- MFMA GEMM 2: C[M,64] = A[M,256] @ B[256,64] ---------------

__global__ __launch_bounds__(256) void gemm2_mfma(const __bf16* __restrict__ A,
                                                  const __bf16* __restrict__ BT,
                                                  __bf16* __restrict__ C, int M) {
    const int K = 256, Nn = 64;
    __shared__ __align__(16) __bf16 Bs[64 * 264];
    __shared__ __align__(16) __bf16 As[128 * 40];
    const int tid = threadIdx.x;
    const int wave = tid >> 6, lane = tid & 63;
    const int quad = lane >> 4, l16 = lane & 15;
    const int bm = blockIdx.x * 128;
#pragma unroll
    for (int it = 0; it < 8; ++it) {
        int e = tid + it * 256;
        int row = e >> 5, ch = e & 31;
        *(bf16x8*)(Bs + row * 264 + ch * 8) = *(const bf16x8*)(BT + row * 256 + ch * 8);
    }
    f32x4 acc[2][4] = {};
    for (int k0 = 0; k0 < K; k0 += 32) {
#pragma unroll
        for (int it = 0; it < 2; ++it) {
            int e = tid + it * 256;
            int row = e >> 2, ch = e & 3;
            int gm = bm + row;
            bf16x8 v = {};
            if (gm < M) v = *(const bf16x8*)(A + (size_t)gm * K + k0 + ch * 8);
            *(bf16x8*)(As + row * 40 + ch * 8) = v;
        }
        __syncthreads();
        bf16x8 a[2], b[4];
#pragma unroll
        for (int i = 0; i < 2; ++i)
            a[i] = *(bf16x8*)(As + (wave * 32 + i * 16 + l16) * 40 + quad * 8);
#pragma unroll
        for (int j = 0; j < 4; ++j)
            b[j] = *(bf16x8*)(Bs + (j * 16 + l16) * 264 + k0 + quad * 8);
#pragma unroll
        for (int i = 0; i < 2; ++i)
#pragma unroll
            for (int j = 0; j < 4; ++j)
                acc[i][j] = __builtin_amdgcn_mfma_f32_16x16x32_bf16(a[i], b[j], acc[i][j], 0, 0, 0);
        __syncthreads();
    }
#pragma unroll
    for (int i = 0; i < 2; ++i)
#pragma unroll
        for (int j = 0; j < 4; ++j)
#pragma unroll
            for (int rr = 0; rr < 4; ++rr) {
                int row = bm + wave * 32 + i * 16 + quad * 4 + rr;
                int col = j * 16 + l16;
                if (row < M) C[(size_t)row * Nn + col] = (__bf16)acc[i][j][rr];
            }
}

// ---------------- pull-mode SpMM ----------------

__global__ __launch_bounds__(256) void spmm256_fp8(const unsigned char* __restrict__ h,
                                                   const int* __restrict__ rp,
                                                   const int2* __restrict__ ep,
                                                   const float* __restrict__ bias,
                                                   __bf16* __restrict__ out, int n) {
    int node = blockIdx.x * 4 + (threadIdx.x >> 6);
    if (node >= n) return;
    int lane = threadIdx.x & 63;
    int half = lane >> 5, c = lane & 31;
    int e0 = rp[node], e1 = rp[node + 1];
    float acc[8] = {};
    for (int e = e0; e < e1; e += 8) {
#pragma unroll
        for (int u = 0; u < 4; ++u) {
            int ee = e + u * 2 + half;
            int cl = min(ee, e1 - 1);
            int2 p = ep[cl];
            float w = (ee < e1) ? __int_as_float(p.y) : 0.f;
            uint2 v = *(const uint2*)(h + (size_t)p.x * 256 + c * 8);
            f32x2 f0 = __builtin_amdgcn_cvt_pk_f32_fp8(v.x, false);
            f32x2 f1 = __builtin_amdgcn_cvt_pk_f32_fp8(v.x, true);
            f32x2 f2 = __builtin_amdgcn_cvt_pk_f32_fp8(v.y, false);
            f32x2 f3 = __builtin_amdgcn_cvt_pk_f32_fp8(v.y, true);
            acc[0] = fmaf(w, f0.x, acc[0]); acc[1] = fmaf(w, f0.y, acc[1]);
            acc[2] = fmaf(w, f1.x, acc[2]); acc[3] = fmaf(w, f1.y, acc[3]);
            acc[4] = fmaf(w, f2.x, acc[4]); acc[5] = fmaf(w, f2.y, acc[5]);
            acc[6] = fmaf(w, f3.x, acc[6]); acc[7] = fmaf(w, f3.y, acc[7]);
        }
    }
#pragma unroll
    for (int i = 0; i < 8; ++i) acc[i] += __shfl_xor(acc[i], 32);
    if (half == 0) {
        float4 b0 = *(const float4*)(bias + c * 8);
        float4 b1 = *(const float4*)(bias + c * 8 + 4);
        bf16x8 o;
        o[0] = (__bf16)fmaxf(acc[0] + b0.x, 0.f);
        o[1] = (__bf16)fmaxf(acc[1] + b0.y, 0.f);
        o[2] = (__bf16)fmaxf(acc[2] + b0.z, 0.f);
        o[3] = (__bf16)fmaxf(acc[3] + b0.w, 0.f);
        o[4] = (__bf16)fmaxf(acc[4] + b1.x, 0.f);
        o[5] = (__bf16)fmaxf(acc[5] + b1.y, 0.f);
        o[6] = (__bf16)fmaxf(acc[6] + b1.z, 0.f);
        o[7] = (__bf16)fmaxf(acc[7] + b1.w, 0.f);
        *(bf16x8*)(out + (size_t)node * 256 + c * 8) = o;
    }
}

__global__ __launch_bounds__(256) void spmm64_a(const __bf16* __restrict__ h,
                                                const int* __restrict__ rp,
                                                const int2* __restrict__ ep,
                                                __bf16* __restrict__ out,
                                                float* __restrict__ degw, int n) {
    int node = blockIdx.x * 4 + (threadIdx.x >> 6);
    if (node >= n) return;
    int lane = threadIdx.x & 63;
    int g = lane >> 3, c = lane & 7;
    int e0 = rp[node], e1 = rp[node + 1];
    float acc[8] = {};
    float ws = 0.f;
    for (int e = e0; e < e1; e += 16) {
#pragma unroll
        for (int u = 0; u < 2; ++u) {
            int ee = e + u * 8 + g;
            int cl = min(ee, e1 - 1);
            int2 p = ep[cl];
            float w = (ee < e1) ? __int_as_float(p.y) : 0.f;
            bf16x8 v = *(const bf16x8*)(h + (size_t)p.x * 64 + c * 8);
#pragma unroll
            for (int i = 0; i < 8; ++i) acc[i] = fmaf(w, (float)v[i], acc[i]);
            ws += w;
        }
    }
#pragma unroll
    for (int off = 8; off <= 32; off <<= 1) {
        ws += __shfl_xor(ws, off);
#pragma unroll
        for (int i = 0; i < 8; ++i) acc[i] += __shfl_xor(acc[i], off);
    }
    if (lane == 0) degw[node] = ws;
    if (g == 0) {
        bf16x8 o;
#pragma unroll
        for (int i = 0; i < 8; ++i) o[i] = (__bf16)acc[i];
        *(bf16x8*)(out + (size_t)node * 64 + c * 8) = o;
    }
}

__global__ __launch_bounds__(256) void spmm64_b(const __bf16* __restrict__ h,
                                                const int* __restrict__ rp,
                                                const int2* __restrict__ ep,
                                                const float* __restrict__ degw,
                                                const float* __restrict__ cvec,
                                                const float* __restrict__ r,
                                                float* __restrict__ out, int n) {
    int node = blockIdx.x * 4 + (threadIdx.x >> 6);
    if (node >= n) return;
    int lane = threadIdx.x & 63;
    int g = lane >> 3, c = lane & 7;
    int e0 = rp[node], e1 = rp[node + 1];
    float acc[8] = {};
    for (int e = e0; e < e1; e += 16) {
#pragma unroll
        for (int u = 0; u < 2; ++u) {
            int ee = e + u * 8 + g;
            int cl = min(ee, e1 - 1);
            int2 p = ep[cl];
            float w = (ee < e1) ? __int_as_float(p.y) : 0.f;
            bf16x8 v = *(const bf16x8*)(h + (size_t)p.x * 64 + c * 8);
#pragma unroll
            for (int i = 0; i < 8; ++i) acc[i] = fmaf(w, (float)v[i], acc[i]);
        }
    }
#pragma unroll
    for (int off = 8; off <= 32; off <<= 1)
#pragma unroll
        for (int i = 0; i < 8; ++i) acc[i] += __shfl_xor(acc[i], off);
    float dw = degw[node];
    float4 c0 = *(const float4*)(cvec + c * 8), c1 = *(const float4*)(cvec + c * 8 + 4);
    float4 r0 = *(const float4*)(r + c * 8),    r1 = *(const float4*)(r + c * 8 + 4);
    float v[8];
    v[0] = acc[0] + dw * c0.x + r0.x; v[1] = acc[1] + dw * c0.y + r0.y;
    v[2] = acc[2] + dw * c0.z + r0.z; v[3] = acc[3] + dw * c0.w + r0.w;
    v[4] = acc[4] + dw * c1.x + r1.x; v[5] = acc[5] + dw * c1.y + r1.y;
    v[6] = acc[6] + dw * c1.z + r1.z; v[7] = acc[7] + dw * c1.w + r1.w;
    float m = v[0];
#pragma unroll
    for (int i = 1; i < 8; ++i) m = fmaxf(m, v[i]);
#pragma unroll
    for (int off = 1; off <= 4; off <<= 1) m = fmaxf(m, __shfl_xor(m, off));
    float s = 0.f;
#pragma unroll
    for (int i = 0; i < 8; ++i) s += __expf(v[i] - m);
#pragma unroll
    for (int off = 1; off <= 4; off <<= 1) s += __shfl_xor(s, off);
    float ls = m + __logf(s);
    if (g == 0) {
        float4 o0 = make_float4(v[0] - ls, v[1] - ls, v[2] - ls, v[3] - ls);
        float4 o1 = make_float4(v[4] - ls, v[5] - ls, v[6] - ls, v[7] - ls);
        *(float4*)(out + (size_t)node * 64 + c * 8) = o0;
        *(float4*)(out + (size_t)node * 64 + c * 8 + 4) = o1;
    }
}

// ---------------------------------------------------------------------------

extern "C" void kernel_launch(void* const* d_in, const int* in_sizes, int n_in,
                              void* d_out, int out_size, void* d_ws, size_t ws_size,
                              hipStream_t stream) {
    const float* x   = (const float*)d_in[0];
    const int*   src = (const int*)d_in[1];
    const int*   dst = (const int*)d_in[2];
    const float* ew  = (const float*)d_in[3];
    const float* W1  = (const float*)d_in[4];
    const float* b1  = (const float*)d_in[5];
    const float* W2  = (const float*)d_in[6];
    const float* b2  = (const float*)d_in[7];
    const float* W3  = (const float*)d_in[8];
    const float* r   = (const float*)d_in[9];

    const int N = in_sizes[0] / 512;       // 100000
    const int E = in_sizes[1];             // 3200000
    const int nb = (N + 255) / 256;        // scan blocks
    const int NB = (N + 511) >> 9;         // dst buckets (196)
    const int buckcap = (((E / NB) * 5) / 4 + 255) & ~255;   // ~20480

    // ---- workspace layout ----
    char* ws = (char*)d_ws;
    __bf16* h1 = (__bf16*)ws;                            // N*256 bf16 @ 0
    char* regB = ws + (size_t)N * 512;
    unsigned char* h0f = (unsigned char*)regB;           // N*256 fp8
    __bf16* g3   = (__bf16*)regB;                        // reuse after spmm256
    __bf16* t1   = (__bf16*)(regB + (size_t)N * 128);
    float*  degw = (float*)(regB + (size_t)N * 256);
    char* regC = regB + (size_t)N * 512;
    __bf16* W1T  = (__bf16*)regC;                        // 512*256 bf16
    __bf16* W23T = (__bf16*)(regC + 512 * 256 * 2);      // 64*256 bf16
    float*  cvec = (float*)(regC + 512 * 256 * 2 + 64 * 256 * 2);
    int* bsum = (int*)(regC + 512 * 256 * 2 + 64 * 256 * 2 + 256);
    int* boff = bsum + 1024;
    char* regD = regC + 512 * 1024;
    int*  rp   = (int*)regD;                             // N+1
    int*  cnt  = rp + (N + 1);                           // N   (zeroed)
    int*  gcnt = cnt + N;                                // 256 (zeroed)
    int2* ep   = (int2*)(gcnt + 256);                    // E pairs
    int4* tb   = (int4*)(ep + E);                        // NB*buckcap entries

    // ---- CSR build (2-phase bucket sort) ----
    hipMemsetAsync(cnt, 0, (size_t)(N + 256) * sizeof(int), stream);
    bucket_scatter<<<(E + TILE - 1) / TILE, 1024, 0, stream>>>(src, dst, ew, cnt,
                                                               gcnt, tb, E, buckcap);
    scan_block<<<nb, 256, 0, stream>>>(cnt, rp, bsum, N);
    scan_bsum<<<1, 1024, 0, stream>>>(bsum, boff, nb, rp + N);
    add_boff<<<nb, 256, 0, stream>>>(rp, boff, N);
    bucket_place<<<NB, 1024, 0, stream>>>(tb, gcnt, rp, ep, N, buckcap);

    // ---- precomputes ----
    cast_transpose<<<(512 * 256 + 255) / 256, 256, 0, stream>>>(W1, W1T, 512, 256);
    make_w23t<<<64, 256, 0, stream>>>(W2, W3, W23T);
    make_c<<<1, 64, 0, stream>>>(b2, W3, cvec);

    // ---- layer 1 ----
    gemm1_fused<<<(N + 127) / 128, 512, 0, stream>>>(x, W1T, h0f, N);
    spmm256_fp8<<<(N + 3) / 4, 256, 0, stream>>>(h0f, rp, ep, b1, h1, N);

    // ---- fused layers 2+3 ----
    gemm2_mfma<<<(N + 127) / 128, 256, 0, stream>>>(h1, W23T, g3, N);
    spmm64_a<<<(N + 3) / 4, 256, 0, stream>>>(g3, rp, ep, t1, degw, N);
    spmm64_b<<<(N + 3) / 4, 256, 0, stream>>>(t1, rp, ep, degw, cvec, r, (float*)d_out, N);
}